// Round 8
// baseline (772.909 us; speedup 1.0000x reference)
//
#include <hip/hip_runtime.h>
#include <math.h>
#include <stdint.h>
#include <limits.h>

#define NPTS 32768
#define DIM  256
#define KCB  4096
#define NQ   (NPTS*DIM)

#define EPSN    1e-12f
#define MARGIN1 6.0e-4f
#define F16MIN  6.103515625e-05f

typedef __attribute__((ext_vector_type(8))) _Float16 f16x8;
typedef __attribute__((ext_vector_type(4))) _Float16 f16x4;
typedef __attribute__((ext_vector_type(4))) float    f32x4;

// ws layout (byte offsets), all regions disjoint, total ~3.06 MB
#define WS_EH0   0u        // KCB*DIM f16 (2,097,152 B) normalized codebook
#define WS_SUME  2097152u  // KCB f32
#define WS_EINV  2113536u  // KCB f32
#define WS_XINV  2129920u  // NPTS f32
#define WS_IDX   2260992u  // NPTS i32
#define WS_RCA   2392064u  // 1 i32 (pad 16)
#define WS_RLA   2392080u  // NPTS int4 (512 KB)
#define WS_RCB   2916368u  // 1 i32 (pad 16)
#define WS_RLB   2916384u  // NPTS i32 (128 KB)
#define WS_LOSSP 3047456u  // 2048 f32

__device__ inline unsigned fbits(float f){ union{float f;unsigned u;}v; v.f=f; return v.u; }
__device__ inline float bitsf(unsigned u){ union{float f;unsigned u;}v; v.u=u; return v.f; }
__device__ inline uint64_t dbits(double d){ union{double d;uint64_t u;}v; v.d=d; return v.u; }
__device__ inline _Float16 g16(float v){
    return (fabsf(v) < F16MIN) ? (_Float16)0.0f : (_Float16)v;
}
__device__ inline void gload16(const void* src, void* lds){
    __builtin_amdgcn_global_load_lds((const __attribute__((address_space(1))) void*)src,
                                     (__attribute__((address_space(3))) void*)lds, 16, 0, 0);
}

__global__ void k_init(int* rca, int* rcb) {
    if (threadIdx.x == 0) { *rca = 0; *rcb = 0; }
}

// one wave per input row: inverse norm
__global__ __launch_bounds__(256) void k_norm_x(const float* __restrict__ x,
                                                float* __restrict__ xinv) {
    int w = threadIdx.x >> 6, l = threadIdx.x & 63;
    int row = blockIdx.x * 4 + w;
    float4 v = ((const float4*)x)[row * 64 + l];
    float s = v.x*v.x + v.y*v.y + v.z*v.z + v.w*v.w;
    #pragma unroll
    for (int o = 32; o; o >>= 1) s += __shfl_xor(s, o);
    if (l == 0) xinv[row] = 1.0f / fmaxf(sqrtf(s), EPSN);
}

// one wave per code: f16 normalized row (subnormal-flushed) + fp32 sumsq + invnorm
__global__ __launch_bounds__(256) void k_norm_e(const float* __restrict__ e,
                                                _Float16* __restrict__ eh0,
                                                float* __restrict__ sume,
                                                float* __restrict__ einv) {
    int w = threadIdx.x >> 6, l = threadIdx.x & 63;
    int row = blockIdx.x * 4 + w;
    float4 v = ((const float4*)e)[row * 64 + l];
    float s = v.x*v.x + v.y*v.y + v.z*v.z + v.w*v.w;
    #pragma unroll
    for (int o = 32; o; o >>= 1) s += __shfl_xor(s, o);
    float inv = 1.0f / fmaxf(sqrtf(s), EPSN);
    float4 n = make_float4(v.x*inv, v.y*inv, v.z*inv, v.w*inv);
    f16x4 h0; h0[0]=g16(n.x); h0[1]=g16(n.y); h0[2]=g16(n.z); h0[3]=g16(n.w);
    ((f16x4*)eh0)[row * 64 + l] = h0;
    float s2 = n.x*n.x + n.y*n.y + n.z*n.z + n.w*n.w;
    #pragma unroll
    for (int o = 32; o; o >>= 1) s2 += __shfl_xor(s2, o);
    if (l == 0) { sume[row] = s2; einv[row] = inv; }
}

// tier 1: f16 MFMA distance argmin with top-3 tracking.
// Flags: listA (d1-d0<MARGIN1) -> candidate rescore {k0,k1,k2};
//        listB (d2-d0<MARGIN1) -> full-K f64 fallback (run after, overwrites).
__global__ __launch_bounds__(256,1) void k_phase1(
    const float* __restrict__ x, const float* __restrict__ xinv,
    const _Float16* __restrict__ eh0, const float* __restrict__ sume,
    int* __restrict__ idx,
    int* __restrict__ rca, int4* __restrict__ rla,
    int* __restrict__ rcb, int* __restrict__ rlb)
{
    __shared__ __align__(16) _Float16 Bs[2][64 * DIM];  // 2 x 32 KB
    const int tid = threadIdx.x;
    const int w = tid >> 6, l = tid & 63;
    const int l15 = l & 15, lhi = l >> 4;
    const int rowbase = blockIdx.x * 128 + w * 32;

    // A fragments: lane holds x_norm[row = l15 (+mi*16)][d = dc*32 + lhi*8 + j]
    f16x8 a[2][8];
    #pragma unroll
    for (int mi = 0; mi < 2; mi++) {
        int row = rowbase + mi*16 + l15;
        float xv = xinv[row];
        const float4* xr = (const float4*)(x + row * DIM);
        #pragma unroll
        for (int dc = 0; dc < 8; dc++) {
            float4 f0 = xr[dc*8 + lhi*2];
            float4 f1 = xr[dc*8 + lhi*2 + 1];
            f16x8 av;
            av[0]=g16(f0.x*xv); av[1]=g16(f0.y*xv);
            av[2]=g16(f0.z*xv); av[3]=g16(f0.w*xv);
            av[4]=g16(f1.x*xv); av[5]=g16(f1.y*xv);
            av[6]=g16(f1.z*xv); av[7]=g16(f1.w*xv);
            a[mi][dc] = av;
        }
    }

    uint64_t t0[8], t1[8], t2[8];
    #pragma unroll
    for (int s = 0; s < 8; s++) { t0[s]=~0ull; t1[s]=~0ull; t2[s]=~0ull; }

    auto stage = [&](int kt, int buf) {
        const _Float16* gbase = eh0 + kt * 64 * DIM;
        #pragma unroll
        for (int i = 0; i < 8; i++) {
            int dstbyte = (w*512 + i*64 + l) << 4;
            int col = dstbyte >> 9;                  // 512 B per code row
            int off = dstbyte & 511;
            int srcoff = off ^ ((col & 7) << 4);     // inverse-swizzled source
            const void* src = (const void*)((const char*)(gbase + col*DIM) + srcoff);
            void* dst = (void*)((char*)(&Bs[buf][0]) + ((w*512 + i*64) << 4)); // wave-uniform base
            gload16(src, dst);
        }
    };

    stage(0, 0);
    for (int kt = 0; kt < 64; kt++) {
        __syncthreads();                 // drains vmcnt(0): current tile ready
        if (kt < 63) stage(kt + 1, (kt + 1) & 1);
        const int buf = kt & 1;

        float ses[4];
        #pragma unroll
        for (int ni = 0; ni < 4; ni++) ses[ni] = sume[kt*64 + ni*16 + l15];

        f32x4 acc[2][4];
        #pragma unroll
        for (int mi = 0; mi < 2; mi++)
            #pragma unroll
            for (int ni = 0; ni < 4; ni++)
                acc[mi][ni] = (f32x4){0.f, 0.f, 0.f, 0.f};

        #pragma unroll
        for (int dc = 0; dc < 8; dc++) {
            #pragma unroll
            for (int ni = 0; ni < 4; ni++) {
                int col = ni*16 + l15;
                int off = (col*512 + dc*64 + lhi*16) ^ ((col & 7) << 4);
                f16x8 b = *(const f16x8*)((const char*)(&Bs[buf][0]) + off);
                acc[0][ni] = __builtin_amdgcn_mfma_f32_16x16x32_f16(a[0][dc], b, acc[0][ni], 0, 0, 0);
                acc[1][ni] = __builtin_amdgcn_mfma_f32_16x16x32_f16(a[1][dc], b, acc[1][ni], 0, 0, 0);
            }
        }

        #pragma unroll
        for (int ni = 0; ni < 4; ni++) {
            int col = kt*64 + ni*16 + l15;
            #pragma unroll
            for (int mi = 0; mi < 2; mi++) {
                #pragma unroll
                for (int r = 0; r < 4; r++) {
                    float db = 4.0f + ses[ni] - 2.0f * acc[mi][ni][r];   // > 0 always
                    uint64_t key = ((uint64_t)fbits(db) << 32) | (unsigned)col;
                    int s = mi*4 + r;
                    if (key < t2[s]) {
                        if (key < t1[s]) {
                            t2[s] = t1[s];
                            if (key < t0[s]) { t1[s] = t0[s]; t0[s] = key; }
                            else t1[s] = key;
                        } else t2[s] = key;
                    }
                }
            }
        }
    }

    // merge top-3 across the 16 col-lanes (butterfly over l15 bits)
    #pragma unroll
    for (int s = 0; s < 8; s++) {
        uint64_t a0 = t0[s], a1 = t1[s], a2 = t2[s];
        #pragma unroll
        for (int m = 1; m < 16; m <<= 1) {
            uint64_t b0 = __shfl_xor(a0, m), b1 = __shfl_xor(a1, m), b2 = __shfl_xor(a2, m);
            uint64_t n0  = a0 < b0 ? a0 : b0;
            uint64_t xx  = a0 < b0 ? b0 : a0;
            uint64_t mn1 = a1 < b1 ? a1 : b1;
            uint64_t mx1 = a1 < b1 ? b1 : a1;
            uint64_t n1  = xx < mn1 ? xx : mn1;
            uint64_t c1  = xx < mn1 ? mn1 : xx;
            uint64_t mn2 = a2 < b2 ? a2 : b2;
            uint64_t n2  = c1 < mx1 ? c1 : mx1;
            n2 = n2 < mn2 ? n2 : mn2;
            a0 = n0; a1 = n1; a2 = n2;
        }
        t0[s] = a0; t1[s] = a1; t2[s] = a2;
    }

    if (l15 == 0) {
        #pragma unroll
        for (int s = 0; s < 8; s++) {
            int mi = s >> 2, r = s & 3;
            int row = rowbase + mi*16 + lhi*4 + r;
            int k0 = (int)(unsigned)(t0[s] & 0xFFFFFFFFull);
            idx[row] = k0;
            float d0 = bitsf((unsigned)(t0[s] >> 32));
            float d1 = bitsf((unsigned)(t1[s] >> 32));
            float d2 = bitsf((unsigned)(t2[s] >> 32));
            if (d1 - d0 < MARGIN1) {
                int k1 = (int)(unsigned)(t1[s] & 0xFFFFFFFFull);
                int k2 = (int)(unsigned)(t2[s] & 0xFFFFFFFFull);
                int p = atomicAdd(rca, 1);
                if (p < NPTS) rla[p] = make_int4(row, k0, k1, k2);
                if (d2 - d0 < MARGIN1) {
                    int q = atomicAdd(rcb, 1);
                    if (q < NPTS) rlb[q] = row;
                }
            }
        }
    }
}

// tier 2a: f64 rescore of the 3 candidates, one wave per flagged row
__global__ __launch_bounds__(256) void k_cand(
    const float* __restrict__ x, const float* __restrict__ emb,
    const float* __restrict__ xinv, const float* __restrict__ einv,
    const float* __restrict__ sume,
    const int* __restrict__ rca, const int4* __restrict__ rla,
    int* __restrict__ idx)
{
    int cnt = *rca; if (cnt > NPTS) cnt = NPTS;
    const int w = threadIdx.x >> 6, l = threadIdx.x & 63;
    for (int r = blockIdx.x * 4 + w; r < cnt; r += gridDim.x * 4) {
        int4 ent = rla[r];
        int row = ent.x;
        float xv = xinv[row];
        float4 xf = ((const float4*)x)[row * 64 + l];
        double x0 = (double)(xf.x) * (double)xv, x1 = (double)(xf.y) * (double)xv;
        double x2 = (double)(xf.z) * (double)xv, x3 = (double)(xf.w) * (double)xv;
        int ks[3] = {ent.y, ent.z, ent.w};
        double d[3];
        #pragma unroll
        for (int c = 0; c < 3; c++) {
            int k = ks[c];
            float ev = einv[k];
            float4 e4 = ((const float4*)emb)[k * 64 + l];
            d[c] = x0 * (double)(e4.x * ev) + x1 * (double)(e4.y * ev)
                 + x2 * (double)(e4.z * ev) + x3 * (double)(e4.w * ev);
        }
        #pragma unroll
        for (int o = 32; o; o >>= 1) {
            #pragma unroll
            for (int c = 0; c < 3; c++) d[c] += __shfl_xor(d[c], o);
        }
        if (l == 0) {
            uint64_t best = ~0ull;
            #pragma unroll
            for (int c = 0; c < 3; c++) {
                double dist = 4.0 + (double)sume[ks[c]] - 2.0 * d[c];
                uint64_t key = (dbits(dist) & 0xFFFFFFFFFFFFF000ull) | (unsigned)ks[c];
                best = key < best ? key : best;
            }
            idx[row] = (int)(best & 0xFFFull);
        }
    }
}

// tier 2b: full-K f64 fallback, one block per row, 8 lanes per code,
// LDS-staged coalesced code tiles (32 codes x 256 dims f32 per pass).
__global__ __launch_bounds__(256) void k_full(
    const float* __restrict__ x, const float* __restrict__ emb,
    const float* __restrict__ xinv, const float* __restrict__ einv,
    const float* __restrict__ sume,
    const int* __restrict__ rcb, const int* __restrict__ rlb,
    int* __restrict__ idx)
{
    __shared__ __align__(16) float xs[DIM];
    __shared__ __align__(16) float4 Es[32][64];
    __shared__ uint64_t sk[256];
    const int tid = threadIdx.x;
    int cnt = *rcb; if (cnt > NPTS) cnt = NPTS; if (cnt <= 0) return;

    for (int r = blockIdx.x; r < cnt; r += gridDim.x) {
        int row = rlb[r];
        __syncthreads();
        xs[tid] = x[row * DIM + tid] * xinv[row];
        __syncthreads();
        const float4* xs4 = (const float4*)xs;
        uint64_t best = ~0ull;
        const int c = tid >> 3, sub = tid & 7;

        for (int kt = 0; kt < 128; kt++) {
            #pragma unroll
            for (int s = 0; s < 8; s++) {
                int i4 = s * 256 + tid;
                int code = i4 >> 6, pos = i4 & 63;
                Es[code][pos] = ((const float4*)emb)[(kt*32 + code) * 64 + pos];
            }
            __syncthreads();
            int k = kt * 32 + c;
            float ev = einv[k];
            double dp = 0.0;
            #pragma unroll
            for (int i = 0; i < 8; i++) {
                float4 ef = Es[c][sub*8 + i];
                float4 xf = xs4[sub*8 + i];
                dp += (double)xf.x * (double)(ef.x * ev)
                    + (double)xf.y * (double)(ef.y * ev)
                    + (double)xf.z * (double)(ef.z * ev)
                    + (double)xf.w * (double)(ef.w * ev);
            }
            #pragma unroll
            for (int o = 4; o; o >>= 1) dp += __shfl_xor(dp, o);
            if (sub == 0) {
                double dist = 4.0 + (double)sume[k] - 2.0 * dp;
                uint64_t key = (dbits(dist) & 0xFFFFFFFFFFFFF000ull) | (unsigned)k;
                best = key < best ? key : best;
            }
            __syncthreads();
        }
        sk[tid] = best;
        __syncthreads();
        for (int s = 128; s > 0; s >>= 1) {
            if (tid < s) { if (sk[tid+s] < sk[tid]) sk[tid] = sk[tid+s]; }
            __syncthreads();
        }
        if (tid == 0) idx[row] = (int)(sk[0] & 0xFFFull);
        __syncthreads();
    }
}

// gather raw embeddings, straight-through output, loss partials, idx-as-float
__global__ __launch_bounds__(256) void k_gather(const float* __restrict__ x,
                                                const float* __restrict__ emb,
                                                const int* __restrict__ idx,
                                                float* __restrict__ out,
                                                float* __restrict__ lossp) {
    int t = blockIdx.x * 256 + threadIdx.x;
    float ls = 0.f;
    #pragma unroll
    for (int s = 0; s < 4; ++s) {
        int i4 = t + s * 524288;
        int n = i4 >> 6, c4 = i4 & 63;
        int id = idx[n];
        float4 f = ((const float4*)x)[i4];
        float4 q = ((const float4*)emb)[id * 64 + c4];
        float dx = q.x - f.x, dy = q.y - f.y, dz = q.z - f.z, dw = q.w - f.w;
        float4 o = make_float4(f.x + dx, f.y + dy, f.z + dz, f.w + dw);
        ((float4*)out)[i4] = o;
        ls += dx*dx + dy*dy + dz*dz + dw*dw;
        if (c4 == 0) out[NQ + 1 + n] = (float)id;
    }
    #pragma unroll
    for (int o = 32; o; o >>= 1) ls += __shfl_xor(ls, o);
    __shared__ float wsum[4];
    int wid = threadIdx.x >> 6, lane = threadIdx.x & 63;
    if (lane == 0) wsum[wid] = ls;
    __syncthreads();
    if (threadIdx.x == 0) lossp[blockIdx.x] = wsum[0] + wsum[1] + wsum[2] + wsum[3];
}

__global__ __launch_bounds__(256) void k_finalize(const float* __restrict__ lossp,
                                                  float* __restrict__ out) {
    double s = 0;
    for (int i = threadIdx.x; i < 2048; i += 256) s += (double)lossp[i];
    #pragma unroll
    for (int o = 32; o; o >>= 1) s += __shfl_xor(s, o);
    __shared__ double wd[4];
    int wid = threadIdx.x >> 6, lane = threadIdx.x & 63;
    if (lane == 0) wd[wid] = s;
    __syncthreads();
    if (threadIdx.x == 0)
        out[NQ] = (float)(0.25 * ((wd[0] + wd[1] + wd[2] + wd[3]) / (double)NQ));
}

extern "C" void kernel_launch(void* const* d_in, const int* in_sizes, int n_in,
                              void* d_out, int out_size, void* d_ws, size_t ws_size,
                              hipStream_t stream) {
    const float* x   = (const float*)d_in[0];
    const float* emb = (const float*)d_in[1];
    char* ws = (char*)d_ws;
    _Float16* eh0 = (_Float16*)(ws + WS_EH0);
    float* sume  = (float*)(ws + WS_SUME);
    float* einv  = (float*)(ws + WS_EINV);
    float* xinv  = (float*)(ws + WS_XINV);
    int*   idx   = (int*)  (ws + WS_IDX);
    int*   rca   = (int*)  (ws + WS_RCA);
    int4*  rla   = (int4*) (ws + WS_RLA);
    int*   rcb   = (int*)  (ws + WS_RCB);
    int*   rlb   = (int*)  (ws + WS_RLB);
    float* lossp = (float*)(ws + WS_LOSSP);
    float* out = (float*)d_out;

    hipLaunchKernelGGL(k_init,    dim3(1),        dim3(64),  0, stream, rca, rcb);
    hipLaunchKernelGGL(k_norm_x,  dim3(NPTS/4),   dim3(256), 0, stream, x, xinv);
    hipLaunchKernelGGL(k_norm_e,  dim3(KCB/4),    dim3(256), 0, stream, emb, eh0, sume, einv);
    hipLaunchKernelGGL(k_phase1,  dim3(NPTS/128), dim3(256), 0, stream,
                       x, xinv, eh0, sume, idx, rca, rla, rcb, rlb);
    hipLaunchKernelGGL(k_cand,    dim3(1024),     dim3(256), 0, stream,
                       x, emb, xinv, einv, sume, rca, rla, idx);
    hipLaunchKernelGGL(k_full,    dim3(256),      dim3(256), 0, stream,
                       x, emb, xinv, einv, sume, rcb, rlb, idx);
    hipLaunchKernelGGL(k_gather,  dim3(2048),     dim3(256), 0, stream,
                       x, emb, idx, out, lossp);
    hipLaunchKernelGGL(k_finalize,dim3(1),        dim3(256), 0, stream, lossp, out);
}

// Round 9
// 412.364 us; speedup vs baseline: 1.8743x; 1.8743x over previous
//
#include <hip/hip_runtime.h>
#include <math.h>
#include <stdint.h>
#include <limits.h>

#define NPTS 32768
#define DIM  256
#define KCB  4096
#define NQ   (NPTS*DIM)

#define EPSN    1e-12f
#define MARGIN1 6.0e-4f
#define F16MIN  6.103515625e-05f
#define CAPB    4096

typedef __attribute__((ext_vector_type(8))) _Float16 f16x8;
typedef __attribute__((ext_vector_type(4))) _Float16 f16x4;
typedef __attribute__((ext_vector_type(4))) float    f32x4;

// ws layout (byte offsets). First 4MB: EH0 (f16 codebook, first 2MB, used by
// k_phase1) ALIASED with embT (f32 transposed normalized codebook, 4MB,
// written by k_transpose AFTER k_phase1 completes).
#define WS_EH0   0u        // KCB*DIM f16 (2MB) — dead after k_phase1
#define WS_EMBT  0u        // KCB*DIM f32 (4MB) — built after k_phase1
#define WS_SUME  4194304u  // KCB f32
#define WS_EINV  4210688u  // KCB f32
#define WS_XINV  4227072u  // NPTS f32
#define WS_IDX   4358144u  // NPTS i32
#define WS_RCA   4489216u  // 1 i32 (pad 16)
#define WS_RLA   4489232u  // NPTS int2 (256KB)
#define WS_RCB   4751376u  // 1 i32 (pad 16)
#define WS_RLB   4751392u  // NPTS i32 (128KB)
#define WS_BEST  4882464u  // CAPB u64 (32KB)
#define WS_LOSSP 4915232u  // 2048 f32

__device__ inline unsigned fbits(float f){ union{float f;unsigned u;}v; v.f=f; return v.u; }
__device__ inline float bitsf(unsigned u){ union{float f;unsigned u;}v; v.u=u; return v.f; }
__device__ inline uint64_t dbits(double d){ union{double d;uint64_t u;}v; v.d=d; return v.u; }
__device__ inline _Float16 g16(float v){
    return (fabsf(v) < F16MIN) ? (_Float16)0.0f : (_Float16)v;
}
__device__ inline void gload16(const void* src, void* lds){
    __builtin_amdgcn_global_load_lds((const __attribute__((address_space(1))) void*)src,
                                     (__attribute__((address_space(3))) void*)lds, 16, 0, 0);
}

__global__ void k_init(int* rca, int* rcb) {
    if (threadIdx.x == 0) { *rca = 0; *rcb = 0; }
}

// one wave per input row: inverse norm
__global__ __launch_bounds__(256) void k_norm_x(const float* __restrict__ x,
                                                float* __restrict__ xinv) {
    int w = threadIdx.x >> 6, l = threadIdx.x & 63;
    int row = blockIdx.x * 4 + w;
    float4 v = ((const float4*)x)[row * 64 + l];
    float s = v.x*v.x + v.y*v.y + v.z*v.z + v.w*v.w;
    #pragma unroll
    for (int o = 32; o; o >>= 1) s += __shfl_xor(s, o);
    if (l == 0) xinv[row] = 1.0f / fmaxf(sqrtf(s), EPSN);
}

// one wave per code: f16 normalized row (subnormal-flushed) + fp32 sumsq + invnorm
__global__ __launch_bounds__(256) void k_norm_e(const float* __restrict__ e,
                                                _Float16* __restrict__ eh0,
                                                float* __restrict__ sume,
                                                float* __restrict__ einv) {
    int w = threadIdx.x >> 6, l = threadIdx.x & 63;
    int row = blockIdx.x * 4 + w;
    float4 v = ((const float4*)e)[row * 64 + l];
    float s = v.x*v.x + v.y*v.y + v.z*v.z + v.w*v.w;
    #pragma unroll
    for (int o = 32; o; o >>= 1) s += __shfl_xor(s, o);
    float inv = 1.0f / fmaxf(sqrtf(s), EPSN);
    float4 n = make_float4(v.x*inv, v.y*inv, v.z*inv, v.w*inv);
    f16x4 h0; h0[0]=g16(n.x); h0[1]=g16(n.y); h0[2]=g16(n.z); h0[3]=g16(n.w);
    ((f16x4*)eh0)[row * 64 + l] = h0;
    float s2 = n.x*n.x + n.y*n.y + n.z*n.z + n.w*n.w;
    #pragma unroll
    for (int o = 32; o; o >>= 1) s2 += __shfl_xor(s2, o);
    if (l == 0) { sume[row] = s2; einv[row] = inv; }
}

// tier 1: f16 MFMA distance argmin with top-3 tracking.
// listA (d1-d0<M): candidates {k0,k1} packed int2; listB (d2-d0<M): full-K f64.
__global__ __launch_bounds__(256,1) void k_phase1(
    const float* __restrict__ x, const float* __restrict__ xinv,
    const _Float16* __restrict__ eh0, const float* __restrict__ sume,
    int* __restrict__ idx,
    int* __restrict__ rca, int2* __restrict__ rla,
    int* __restrict__ rcb, int* __restrict__ rlb)
{
    __shared__ __align__(16) _Float16 Bs[2][64 * DIM];  // 2 x 32 KB
    const int tid = threadIdx.x;
    const int w = tid >> 6, l = tid & 63;
    const int l15 = l & 15, lhi = l >> 4;
    const int rowbase = blockIdx.x * 128 + w * 32;

    f16x8 a[2][8];
    #pragma unroll
    for (int mi = 0; mi < 2; mi++) {
        int row = rowbase + mi*16 + l15;
        float xv = xinv[row];
        const float4* xr = (const float4*)(x + row * DIM);
        #pragma unroll
        for (int dc = 0; dc < 8; dc++) {
            float4 f0 = xr[dc*8 + lhi*2];
            float4 f1 = xr[dc*8 + lhi*2 + 1];
            f16x8 av;
            av[0]=g16(f0.x*xv); av[1]=g16(f0.y*xv);
            av[2]=g16(f0.z*xv); av[3]=g16(f0.w*xv);
            av[4]=g16(f1.x*xv); av[5]=g16(f1.y*xv);
            av[6]=g16(f1.z*xv); av[7]=g16(f1.w*xv);
            a[mi][dc] = av;
        }
    }

    uint64_t t0[8], t1[8], t2[8];
    #pragma unroll
    for (int s = 0; s < 8; s++) { t0[s]=~0ull; t1[s]=~0ull; t2[s]=~0ull; }

    auto stage = [&](int kt, int buf) {
        const _Float16* gbase = eh0 + kt * 64 * DIM;
        #pragma unroll
        for (int i = 0; i < 8; i++) {
            int dstbyte = (w*512 + i*64 + l) << 4;
            int col = dstbyte >> 9;
            int off = dstbyte & 511;
            int srcoff = off ^ ((col & 7) << 4);     // inverse-swizzled source
            const void* src = (const void*)((const char*)(gbase + col*DIM) + srcoff);
            void* dst = (void*)((char*)(&Bs[buf][0]) + ((w*512 + i*64) << 4));
            gload16(src, dst);
        }
    };

    stage(0, 0);
    for (int kt = 0; kt < 64; kt++) {
        __syncthreads();
        if (kt < 63) stage(kt + 1, (kt + 1) & 1);
        const int buf = kt & 1;

        float ses[4];
        #pragma unroll
        for (int ni = 0; ni < 4; ni++) ses[ni] = sume[kt*64 + ni*16 + l15];

        f32x4 acc[2][4];
        #pragma unroll
        for (int mi = 0; mi < 2; mi++)
            #pragma unroll
            for (int ni = 0; ni < 4; ni++)
                acc[mi][ni] = (f32x4){0.f, 0.f, 0.f, 0.f};

        #pragma unroll
        for (int dc = 0; dc < 8; dc++) {
            #pragma unroll
            for (int ni = 0; ni < 4; ni++) {
                int col = ni*16 + l15;
                int off = (col*512 + dc*64 + lhi*16) ^ ((col & 7) << 4);
                f16x8 b = *(const f16x8*)((const char*)(&Bs[buf][0]) + off);
                acc[0][ni] = __builtin_amdgcn_mfma_f32_16x16x32_f16(a[0][dc], b, acc[0][ni], 0, 0, 0);
                acc[1][ni] = __builtin_amdgcn_mfma_f32_16x16x32_f16(a[1][dc], b, acc[1][ni], 0, 0, 0);
            }
        }

        #pragma unroll
        for (int ni = 0; ni < 4; ni++) {
            int col = kt*64 + ni*16 + l15;
            #pragma unroll
            for (int mi = 0; mi < 2; mi++) {
                #pragma unroll
                for (int r = 0; r < 4; r++) {
                    float db = 4.0f + ses[ni] - 2.0f * acc[mi][ni][r];   // > 0 always
                    uint64_t key = ((uint64_t)fbits(db) << 32) | (unsigned)col;
                    int s = mi*4 + r;
                    if (key < t2[s]) {
                        if (key < t1[s]) {
                            t2[s] = t1[s];
                            if (key < t0[s]) { t1[s] = t0[s]; t0[s] = key; }
                            else t1[s] = key;
                        } else t2[s] = key;
                    }
                }
            }
        }
    }

    // merge top-3 across the 16 col-lanes (butterfly over l15 bits)
    #pragma unroll
    for (int s = 0; s < 8; s++) {
        uint64_t a0 = t0[s], a1 = t1[s], a2 = t2[s];
        #pragma unroll
        for (int m = 1; m < 16; m <<= 1) {
            uint64_t b0 = __shfl_xor(a0, m), b1 = __shfl_xor(a1, m), b2 = __shfl_xor(a2, m);
            uint64_t n0  = a0 < b0 ? a0 : b0;
            uint64_t xx  = a0 < b0 ? b0 : a0;
            uint64_t mn1 = a1 < b1 ? a1 : b1;
            uint64_t mx1 = a1 < b1 ? b1 : a1;
            uint64_t n1  = xx < mn1 ? xx : mn1;
            uint64_t c1  = xx < mn1 ? mn1 : xx;
            uint64_t mn2 = a2 < b2 ? a2 : b2;
            uint64_t n2  = c1 < mx1 ? c1 : mx1;
            n2 = n2 < mn2 ? n2 : mn2;
            a0 = n0; a1 = n1; a2 = n2;
        }
        t0[s] = a0; t1[s] = a1; t2[s] = a2;
    }

    if (l15 == 0) {
        #pragma unroll
        for (int s = 0; s < 8; s++) {
            int mi = s >> 2, r = s & 3;
            int row = rowbase + mi*16 + lhi*4 + r;
            int k0 = (int)(unsigned)(t0[s] & 0xFFFFFFFFull);
            idx[row] = k0;
            float d0 = bitsf((unsigned)(t0[s] >> 32));
            float d1 = bitsf((unsigned)(t1[s] >> 32));
            float d2 = bitsf((unsigned)(t2[s] >> 32));
            if (d1 - d0 < MARGIN1) {
                int k1 = (int)(unsigned)(t1[s] & 0xFFFFFFFFull);
                int p = atomicAdd(rca, 1);
                if (p < NPTS) rla[p] = make_int2(row, (k0 & 0xFFF) | (k1 << 12));
                if (d2 - d0 < MARGIN1) {
                    int q = atomicAdd(rcb, 1);
                    if (q < CAPB) rlb[q] = row;
                }
            }
        }
    }
}

// transposed normalized codebook: embT[d*KCB + k] = emb[k][d] * einv[k].
// Runs AFTER k_phase1 (overwrites the EH0 region). Tiled 64x64 via LDS.
__global__ __launch_bounds__(256) void k_transpose(const float* __restrict__ emb,
                                                   const float* __restrict__ einv,
                                                   float* __restrict__ embT) {
    __shared__ float tile[64][65];
    const int tid = threadIdx.x;
    const int kb = (blockIdx.x & 63) * 64;
    const int db = (blockIdx.x >> 6) * 64;
    #pragma unroll
    for (int s = 0; s < 16; s++) {
        int i = s * 256 + tid;
        int lk = i >> 6, ld = i & 63;
        tile[lk][ld] = emb[(kb + lk) * DIM + db + ld] * einv[kb + lk];
    }
    __syncthreads();
    #pragma unroll
    for (int s = 0; s < 16; s++) {
        int i = s * 256 + tid;
        int ld = i >> 6, lk = i & 63;
        embT[(db + ld) * KCB + kb + lk] = tile[lk][ld];
    }
}

// tier 2a: f64 rescore of the 2 provable candidates, one wave per flagged row
__global__ __launch_bounds__(256) void k_cand(
    const float* __restrict__ x, const float* __restrict__ emb,
    const float* __restrict__ xinv, const float* __restrict__ einv,
    const float* __restrict__ sume,
    const int* __restrict__ rca, const int2* __restrict__ rla,
    int* __restrict__ idx)
{
    int cnt = *rca; if (cnt > NPTS) cnt = NPTS;
    const int w = threadIdx.x >> 6, l = threadIdx.x & 63;
    for (int r = blockIdx.x * 4 + w; r < cnt; r += gridDim.x * 4) {
        int2 ent = rla[r];
        int row = ent.x;
        int k0 = ent.y & 0xFFF, k1 = (ent.y >> 12) & 0xFFF;
        float xv = xinv[row];
        float4 xf = ((const float4*)x)[row * 64 + l];
        double x0 = (double)xf.x * (double)xv, x1 = (double)xf.y * (double)xv;
        double x2 = (double)xf.z * (double)xv, x3 = (double)xf.w * (double)xv;
        int ks[2] = {k0, k1};
        double d[2];
        #pragma unroll
        for (int c = 0; c < 2; c++) {
            int k = ks[c];
            float ev = einv[k];
            float4 e4 = ((const float4*)emb)[k * 64 + l];
            d[c] = x0 * (double)(e4.x * ev) + x1 * (double)(e4.y * ev)
                 + x2 * (double)(e4.z * ev) + x3 * (double)(e4.w * ev);
        }
        #pragma unroll
        for (int o = 32; o; o >>= 1) {
            d[0] += __shfl_xor(d[0], o);
            d[1] += __shfl_xor(d[1], o);
        }
        if (l == 0) {
            double dist0 = 4.0 + (double)sume[k0] - 2.0 * d[0];
            double dist1 = 4.0 + (double)sume[k1] - 2.0 * d[1];
            uint64_t key0 = (dbits(dist0) & 0xFFFFFFFFFFFFF000ull) | (unsigned)k0;
            uint64_t key1 = (dbits(dist1) & 0xFFFFFFFFFFFFF000ull) | (unsigned)k1;
            idx[row] = (int)((key0 < key1 ? key0 : key1) & 0xFFFull);
        }
    }
}

__global__ __launch_bounds__(256) void k_binit(uint64_t* __restrict__ bestu) {
    bestu[blockIdx.x * 256 + threadIdx.x] = ~0ull;
}

// tier 2b: full-K f64, shuffle-free & coalesced: block=(row, 256-code chunk),
// thread owns one code; xs broadcast from LDS, embT read coalesced; atomicMin.
__global__ __launch_bounds__(256) void k_full(
    const float* __restrict__ x, const float* __restrict__ embT,
    const float* __restrict__ xinv, const float* __restrict__ sume,
    const int* __restrict__ rcb, const int* __restrict__ rlb,
    uint64_t* __restrict__ bestu)
{
    __shared__ float xs[DIM];
    int cnt = *rcb; if (cnt > CAPB) cnt = CAPB; if (cnt <= 0) return;
    int items = cnt * 16;
    const int tid = threadIdx.x;
    for (int item = blockIdx.x; item < items; item += gridDim.x) {
        int r = item >> 4, chunk = item & 15;
        int row = rlb[r];
        __syncthreads();
        xs[tid] = x[row * DIM + tid] * xinv[row];
        __syncthreads();
        int k = chunk * 256 + tid;
        const float* et = embT + k;
        double dp0 = 0, dp1 = 0, dp2 = 0, dp3 = 0;
        #pragma unroll 8
        for (int d = 0; d < DIM; d += 4) {
            dp0 += (double)xs[d+0] * (double)et[(d+0) * KCB];
            dp1 += (double)xs[d+1] * (double)et[(d+1) * KCB];
            dp2 += (double)xs[d+2] * (double)et[(d+2) * KCB];
            dp3 += (double)xs[d+3] * (double)et[(d+3) * KCB];
        }
        double dist = 4.0 + (double)sume[k] - 2.0 * ((dp0 + dp1) + (dp2 + dp3));
        uint64_t key = (dbits(dist) & 0xFFFFFFFFFFFFF000ull) | (unsigned)k;
        atomicMin((unsigned long long*)&bestu[r], (unsigned long long)key);
    }
}

__global__ __launch_bounds__(256) void k_ffin(const int* __restrict__ rcb,
                                              const int* __restrict__ rlb,
                                              const uint64_t* __restrict__ bestu,
                                              int* __restrict__ idx) {
    int cnt = *rcb; if (cnt > CAPB) cnt = CAPB;
    int i = blockIdx.x * 256 + threadIdx.x;
    if (i < cnt) idx[rlb[i]] = (int)(bestu[i] & 0xFFFull);
}

// gather raw embeddings, straight-through output, loss partials, idx-as-float
__global__ __launch_bounds__(256) void k_gather(const float* __restrict__ x,
                                                const float* __restrict__ emb,
                                                const int* __restrict__ idx,
                                                float* __restrict__ out,
                                                float* __restrict__ lossp) {
    int t = blockIdx.x * 256 + threadIdx.x;
    float ls = 0.f;
    #pragma unroll
    for (int s = 0; s < 4; ++s) {
        int i4 = t + s * 524288;
        int n = i4 >> 6, c4 = i4 & 63;
        int id = idx[n];
        float4 f = ((const float4*)x)[i4];
        float4 q = ((const float4*)emb)[id * 64 + c4];
        float dx = q.x - f.x, dy = q.y - f.y, dz = q.z - f.z, dw = q.w - f.w;
        float4 o = make_float4(f.x + dx, f.y + dy, f.z + dz, f.w + dw);
        ((float4*)out)[i4] = o;
        ls += dx*dx + dy*dy + dz*dz + dw*dw;
        if (c4 == 0) out[NQ + 1 + n] = (float)id;
    }
    #pragma unroll
    for (int o = 32; o; o >>= 1) ls += __shfl_xor(ls, o);
    __shared__ float wsum[4];
    int wid = threadIdx.x >> 6, lane = threadIdx.x & 63;
    if (lane == 0) wsum[wid] = ls;
    __syncthreads();
    if (threadIdx.x == 0) lossp[blockIdx.x] = wsum[0] + wsum[1] + wsum[2] + wsum[3];
}

__global__ __launch_bounds__(256) void k_finalize(const float* __restrict__ lossp,
                                                  float* __restrict__ out) {
    double s = 0;
    for (int i = threadIdx.x; i < 2048; i += 256) s += (double)lossp[i];
    #pragma unroll
    for (int o = 32; o; o >>= 1) s += __shfl_xor(s, o);
    __shared__ double wd[4];
    int wid = threadIdx.x >> 6, lane = threadIdx.x & 63;
    if (lane == 0) wd[wid] = s;
    __syncthreads();
    if (threadIdx.x == 0)
        out[NQ] = (float)(0.25 * ((wd[0] + wd[1] + wd[2] + wd[3]) / (double)NQ));
}

extern "C" void kernel_launch(void* const* d_in, const int* in_sizes, int n_in,
                              void* d_out, int out_size, void* d_ws, size_t ws_size,
                              hipStream_t stream) {
    const float* x   = (const float*)d_in[0];
    const float* emb = (const float*)d_in[1];
    char* ws = (char*)d_ws;
    _Float16* eh0 = (_Float16*)(ws + WS_EH0);
    float* embT  = (float*)(ws + WS_EMBT);
    float* sume  = (float*)(ws + WS_SUME);
    float* einv  = (float*)(ws + WS_EINV);
    float* xinv  = (float*)(ws + WS_XINV);
    int*   idx   = (int*)  (ws + WS_IDX);
    int*   rca   = (int*)  (ws + WS_RCA);
    int2*  rla   = (int2*) (ws + WS_RLA);
    int*   rcb   = (int*)  (ws + WS_RCB);
    int*   rlb   = (int*)  (ws + WS_RLB);
    uint64_t* bestu = (uint64_t*)(ws + WS_BEST);
    float* lossp = (float*)(ws + WS_LOSSP);
    float* out = (float*)d_out;

    hipLaunchKernelGGL(k_init,     dim3(1),        dim3(64),  0, stream, rca, rcb);
    hipLaunchKernelGGL(k_norm_x,   dim3(NPTS/4),   dim3(256), 0, stream, x, xinv);
    hipLaunchKernelGGL(k_norm_e,   dim3(KCB/4),    dim3(256), 0, stream, emb, eh0, sume, einv);
    hipLaunchKernelGGL(k_phase1,   dim3(NPTS/128), dim3(256), 0, stream,
                       x, xinv, eh0, sume, idx, rca, rla, rcb, rlb);
    hipLaunchKernelGGL(k_transpose,dim3(256),      dim3(256), 0, stream, emb, einv, embT);
    hipLaunchKernelGGL(k_binit,    dim3(CAPB/256), dim3(256), 0, stream, bestu);
    hipLaunchKernelGGL(k_cand,     dim3(1024),     dim3(256), 0, stream,
                       x, emb, xinv, einv, sume, rca, rla, idx);
    hipLaunchKernelGGL(k_full,     dim3(2048),     dim3(256), 0, stream,
                       x, embT, xinv, sume, rcb, rlb, bestu);
    hipLaunchKernelGGL(k_ffin,     dim3(16),       dim3(256), 0, stream, rcb, rlb, bestu, idx);
    hipLaunchKernelGGL(k_gather,   dim3(2048),     dim3(256), 0, stream,
                       x, emb, idx, out, lossp);
    hipLaunchKernelGGL(k_finalize, dim3(1),        dim3(256), 0, stream, lossp, out);
}

// Round 10
// 278.466 us; speedup vs baseline: 2.7756x; 1.4808x over previous
//
#include <hip/hip_runtime.h>
#include <math.h>
#include <stdint.h>
#include <limits.h>

#define NPTS 32768
#define DIM  256
#define KCB  4096
#define NQ   (NPTS*DIM)

#define EPSN    1e-12f
#define MARGIN1 6.0e-4f
#define F16MIN  6.103515625e-05f
#define CAPB    4096
#define KINIT   0x7F800000FFFFFFFFull   /* packed (+INF, k=~0) */

typedef __attribute__((ext_vector_type(8))) _Float16 f16x8;
typedef __attribute__((ext_vector_type(4))) _Float16 f16x4;
typedef __attribute__((ext_vector_type(4))) float    f32x4;

// ws layout (byte offsets). EH0 (f16 codebook, 2MB) aliased with embT (f32
// transposed codebook, 4MB, built AFTER k_phase1).
#define WS_EH0   0u
#define WS_EMBT  0u
#define WS_SUME  4194304u
#define WS_EINV  4210688u
#define WS_XINV  4227072u
#define WS_IDX   4358144u
#define WS_RCA   4489216u
#define WS_RLA   4489232u
#define WS_RCB   4751376u
#define WS_RLB   4751392u
#define WS_BEST  4882464u
#define WS_LOSSP 4915232u

__device__ inline unsigned fbits(float f){ union{float f;unsigned u;}v; v.f=f; return v.u; }
__device__ inline float bitsf(unsigned u){ union{float f;unsigned u;}v; v.u=u; return v.f; }
__device__ inline uint64_t dbits(double d){ union{double d;uint64_t u;}v; v.d=d; return v.u; }
__device__ inline _Float16 g16(float v){
    return (fabsf(v) < F16MIN) ? (_Float16)0.0f : (_Float16)v;
}
__device__ inline void gload16(const void* src, void* lds){
    __builtin_amdgcn_global_load_lds((const __attribute__((address_space(1))) void*)src,
                                     (__attribute__((address_space(3))) void*)lds, 16, 0, 0);
}

__global__ void k_init(int* rca, int* rcb) {
    if (threadIdx.x == 0) { *rca = 0; *rcb = 0; }
}

__global__ __launch_bounds__(256) void k_norm_x(const float* __restrict__ x,
                                                float* __restrict__ xinv) {
    int w = threadIdx.x >> 6, l = threadIdx.x & 63;
    int row = blockIdx.x * 4 + w;
    float4 v = ((const float4*)x)[row * 64 + l];
    float s = v.x*v.x + v.y*v.y + v.z*v.z + v.w*v.w;
    #pragma unroll
    for (int o = 32; o; o >>= 1) s += __shfl_xor(s, o);
    if (l == 0) xinv[row] = 1.0f / fmaxf(sqrtf(s), EPSN);
}

__global__ __launch_bounds__(256) void k_norm_e(const float* __restrict__ e,
                                                _Float16* __restrict__ eh0,
                                                float* __restrict__ sume,
                                                float* __restrict__ einv) {
    int w = threadIdx.x >> 6, l = threadIdx.x & 63;
    int row = blockIdx.x * 4 + w;
    float4 v = ((const float4*)e)[row * 64 + l];
    float s = v.x*v.x + v.y*v.y + v.z*v.z + v.w*v.w;
    #pragma unroll
    for (int o = 32; o; o >>= 1) s += __shfl_xor(s, o);
    float inv = 1.0f / fmaxf(sqrtf(s), EPSN);
    float4 n = make_float4(v.x*inv, v.y*inv, v.z*inv, v.w*inv);
    f16x4 h0; h0[0]=g16(n.x); h0[1]=g16(n.y); h0[2]=g16(n.z); h0[3]=g16(n.w);
    ((f16x4*)eh0)[row * 64 + l] = h0;
    float s2 = n.x*n.x + n.y*n.y + n.z*n.z + n.w*n.w;
    #pragma unroll
    for (int o = 32; o; o >>= 1) s2 += __shfl_xor(s2, o);
    if (l == 0) { sume[row] = s2; einv[row] = inv; }
}

// tier 1: f16 MFMA distance argmin, top-3, 64 rows/block (grid 512 = 2 blk/CU),
// f32-screened epilogue (u64 insert only on candidate top-3 hits).
__global__ __launch_bounds__(256,2) void k_phase1(
    const float* __restrict__ x, const float* __restrict__ xinv,
    const _Float16* __restrict__ eh0, const float* __restrict__ sume,
    int* __restrict__ idx,
    int* __restrict__ rca, int2* __restrict__ rla,
    int* __restrict__ rcb, int* __restrict__ rlb)
{
    __shared__ __align__(16) _Float16 Bs[2][64 * DIM];  // 2 x 32 KB
    const int tid = threadIdx.x;
    const int w = tid >> 6, l = tid & 63;
    const int l15 = l & 15, lhi = l >> 4;
    const int rowbase = blockIdx.x * 64 + w * 16;

    // A fragments: lane holds x_norm[row = rowbase+l15][d = dc*32 + lhi*8 + j]
    f16x8 a[8];
    {
        int row = rowbase + l15;
        float xv = xinv[row];
        const float4* xr = (const float4*)(x + row * DIM);
        #pragma unroll
        for (int dc = 0; dc < 8; dc++) {
            float4 f0 = xr[dc*8 + lhi*2];
            float4 f1 = xr[dc*8 + lhi*2 + 1];
            f16x8 av;
            av[0]=g16(f0.x*xv); av[1]=g16(f0.y*xv);
            av[2]=g16(f0.z*xv); av[3]=g16(f0.w*xv);
            av[4]=g16(f1.x*xv); av[5]=g16(f1.y*xv);
            av[6]=g16(f1.z*xv); av[7]=g16(f1.w*xv);
            a[dc] = av;
        }
    }

    uint64_t t0[4], t1[4], t2[4];
    float d2f[4];
    #pragma unroll
    for (int s = 0; s < 4; s++) { t0[s]=KINIT; t1[s]=KINIT; t2[s]=KINIT; d2f[s]=INFINITY; }

    auto stage = [&](int kt, int buf) {
        const _Float16* gbase = eh0 + kt * 64 * DIM;
        #pragma unroll
        for (int i = 0; i < 8; i++) {
            int dstbyte = (w*512 + i*64 + l) << 4;
            int col = dstbyte >> 9;
            int off = dstbyte & 511;
            int srcoff = off ^ ((col & 7) << 4);     // inverse-swizzled source
            const void* src = (const void*)((const char*)(gbase + col*DIM) + srcoff);
            void* dst = (void*)((char*)(&Bs[buf][0]) + ((w*512 + i*64) << 4));
            gload16(src, dst);
        }
    };

    stage(0, 0);
    for (int kt = 0; kt < 64; kt++) {
        __syncthreads();                 // kt's tile ready; kt-1 reads done
        if (kt < 63) stage(kt + 1, (kt + 1) & 1);
        const int buf = kt & 1;

        float ses[4];
        #pragma unroll
        for (int ni = 0; ni < 4; ni++) ses[ni] = 4.0f + sume[kt*64 + ni*16 + l15];

        f32x4 acc[4];
        #pragma unroll
        for (int ni = 0; ni < 4; ni++) acc[ni] = (f32x4){0.f, 0.f, 0.f, 0.f};

        #pragma unroll
        for (int dc = 0; dc < 8; dc++) {
            #pragma unroll
            for (int ni = 0; ni < 4; ni++) {
                int col = ni*16 + l15;
                int off = (col*512 + dc*64 + lhi*16) ^ ((col & 7) << 4);
                f16x8 b = *(const f16x8*)((const char*)(&Bs[buf][0]) + off);
                acc[ni] = __builtin_amdgcn_mfma_f32_16x16x32_f16(a[dc], b, acc[ni], 0, 0, 0);
            }
        }

        #pragma unroll
        for (int ni = 0; ni < 4; ni++) {
            int col = kt*64 + ni*16 + l15;
            #pragma unroll
            for (int r = 0; r < 4; r++) {
                float db = ses[ni] - 2.0f * acc[ni][r];   // positive
                if (db <= d2f[r]) {                        // rare after warmup
                    uint64_t key = ((uint64_t)fbits(db) << 32) | (unsigned)col;
                    if (key < t2[r]) {
                        if (key < t1[r]) {
                            t2[r] = t1[r];
                            if (key < t0[r]) { t1[r] = t0[r]; t0[r] = key; }
                            else t1[r] = key;
                        } else t2[r] = key;
                        d2f[r] = bitsf((unsigned)(t2[r] >> 32));
                    }
                }
            }
        }
    }

    // merge top-3 across the 16 col-lanes (butterfly over l15 bits)
    #pragma unroll
    for (int s = 0; s < 4; s++) {
        uint64_t a0 = t0[s], a1 = t1[s], a2 = t2[s];
        #pragma unroll
        for (int m = 1; m < 16; m <<= 1) {
            uint64_t b0 = __shfl_xor(a0, m), b1 = __shfl_xor(a1, m), b2 = __shfl_xor(a2, m);
            uint64_t n0  = a0 < b0 ? a0 : b0;
            uint64_t xx  = a0 < b0 ? b0 : a0;
            uint64_t mn1 = a1 < b1 ? a1 : b1;
            uint64_t mx1 = a1 < b1 ? b1 : a1;
            uint64_t n1  = xx < mn1 ? xx : mn1;
            uint64_t c1  = xx < mn1 ? mn1 : xx;
            uint64_t mn2 = a2 < b2 ? a2 : b2;
            uint64_t n2  = c1 < mx1 ? c1 : mx1;
            n2 = n2 < mn2 ? n2 : mn2;
            a0 = n0; a1 = n1; a2 = n2;
        }
        t0[s] = a0; t1[s] = a1; t2[s] = a2;
    }

    if (l15 == 0) {
        #pragma unroll
        for (int r = 0; r < 4; r++) {
            int row = rowbase + lhi*4 + r;
            int k0 = (int)(unsigned)(t0[r] & 0xFFFFFFFFull);
            idx[row] = k0;
            float d0 = bitsf((unsigned)(t0[r] >> 32));
            float d1 = bitsf((unsigned)(t1[r] >> 32));
            float d2 = bitsf((unsigned)(t2[r] >> 32));
            if (d1 - d0 < MARGIN1) {
                int k1 = (int)(unsigned)(t1[r] & 0xFFFFFFFFull);
                int p = atomicAdd(rca, 1);
                if (p < NPTS) rla[p] = make_int2(row, (k0 & 0xFFF) | (k1 << 12));
                if (d2 - d0 < MARGIN1) {
                    int q = atomicAdd(rcb, 1);
                    if (q < CAPB) rlb[q] = row;
                }
            }
        }
    }
}

// transposed normalized codebook (after k_phase1; overwrites EH0 region)
__global__ __launch_bounds__(256) void k_transpose(const float* __restrict__ emb,
                                                   const float* __restrict__ einv,
                                                   float* __restrict__ embT) {
    __shared__ float tile[64][65];
    const int tid = threadIdx.x;
    const int kb = (blockIdx.x & 63) * 64;
    const int db = (blockIdx.x >> 6) * 64;
    #pragma unroll
    for (int s = 0; s < 16; s++) {
        int i = s * 256 + tid;
        int lk = i >> 6, ld = i & 63;
        tile[lk][ld] = emb[(kb + lk) * DIM + db + ld] * einv[kb + lk];
    }
    __syncthreads();
    #pragma unroll
    for (int s = 0; s < 16; s++) {
        int i = s * 256 + tid;
        int ld = i >> 6, lk = i & 63;
        embT[(db + ld) * KCB + kb + lk] = tile[lk][ld];
    }
}

// tier 2a: f64 rescore of the 2 provable candidates, one wave per flagged row
__global__ __launch_bounds__(256) void k_cand(
    const float* __restrict__ x, const float* __restrict__ emb,
    const float* __restrict__ xinv, const float* __restrict__ einv,
    const float* __restrict__ sume,
    const int* __restrict__ rca, const int2* __restrict__ rla,
    int* __restrict__ idx)
{
    int cnt = *rca; if (cnt > NPTS) cnt = NPTS;
    const int w = threadIdx.x >> 6, l = threadIdx.x & 63;
    for (int r = blockIdx.x * 4 + w; r < cnt; r += gridDim.x * 4) {
        int2 ent = rla[r];
        int row = ent.x;
        int k0 = ent.y & 0xFFF, k1 = (ent.y >> 12) & 0xFFF;
        float xv = xinv[row];
        float4 xf = ((const float4*)x)[row * 64 + l];
        double x0 = (double)xf.x * (double)xv, x1 = (double)xf.y * (double)xv;
        double x2 = (double)xf.z * (double)xv, x3 = (double)xf.w * (double)xv;
        int ks[2] = {k0, k1};
        double d[2];
        #pragma unroll
        for (int c = 0; c < 2; c++) {
            int k = ks[c];
            float ev = einv[k];
            float4 e4 = ((const float4*)emb)[k * 64 + l];
            d[c] = x0 * (double)(e4.x * ev) + x1 * (double)(e4.y * ev)
                 + x2 * (double)(e4.z * ev) + x3 * (double)(e4.w * ev);
        }
        #pragma unroll
        for (int o = 32; o; o >>= 1) {
            d[0] += __shfl_xor(d[0], o);
            d[1] += __shfl_xor(d[1], o);
        }
        if (l == 0) {
            double dist0 = 4.0 + (double)sume[k0] - 2.0 * d[0];
            double dist1 = 4.0 + (double)sume[k1] - 2.0 * d[1];
            uint64_t key0 = (dbits(dist0) & 0xFFFFFFFFFFFFF000ull) | (unsigned)k0;
            uint64_t key1 = (dbits(dist1) & 0xFFFFFFFFFFFFF000ull) | (unsigned)k1;
            idx[row] = (int)((key0 < key1 ? key0 : key1) & 0xFFFull);
        }
    }
}

__global__ __launch_bounds__(256) void k_binit(uint64_t* __restrict__ bestu) {
    bestu[blockIdx.x * 256 + threadIdx.x] = ~0ull;
}

// tier 2b: full-K f64, shuffle-free coalesced, block=(row,chunk), atomicMin
__global__ __launch_bounds__(256) void k_full(
    const float* __restrict__ x, const float* __restrict__ embT,
    const float* __restrict__ xinv, const float* __restrict__ sume,
    const int* __restrict__ rcb, const int* __restrict__ rlb,
    uint64_t* __restrict__ bestu)
{
    __shared__ float xs[DIM];
    int cnt = *rcb; if (cnt > CAPB) cnt = CAPB; if (cnt <= 0) return;
    int items = cnt * 16;
    const int tid = threadIdx.x;
    for (int item = blockIdx.x; item < items; item += gridDim.x) {
        int r = item >> 4, chunk = item & 15;
        int row = rlb[r];
        __syncthreads();
        xs[tid] = x[row * DIM + tid] * xinv[row];
        __syncthreads();
        int k = chunk * 256 + tid;
        const float* et = embT + k;
        double dp0 = 0, dp1 = 0, dp2 = 0, dp3 = 0;
        #pragma unroll 8
        for (int d = 0; d < DIM; d += 4) {
            dp0 += (double)xs[d+0] * (double)et[(d+0) * KCB];
            dp1 += (double)xs[d+1] * (double)et[(d+1) * KCB];
            dp2 += (double)xs[d+2] * (double)et[(d+2) * KCB];
            dp3 += (double)xs[d+3] * (double)et[(d+3) * KCB];
        }
        double dist = 4.0 + (double)sume[k] - 2.0 * ((dp0 + dp1) + (dp2 + dp3));
        uint64_t key = (dbits(dist) & 0xFFFFFFFFFFFFF000ull) | (unsigned)k;
        atomicMin((unsigned long long*)&bestu[r], (unsigned long long)key);
    }
}

__global__ __launch_bounds__(256) void k_ffin(const int* __restrict__ rcb,
                                              const int* __restrict__ rlb,
                                              const uint64_t* __restrict__ bestu,
                                              int* __restrict__ idx) {
    int cnt = *rcb; if (cnt > CAPB) cnt = CAPB;
    int i = blockIdx.x * 256 + threadIdx.x;
    if (i < cnt) idx[rlb[i]] = (int)(bestu[i] & 0xFFFull);
}

// gather raw embeddings, straight-through output, loss partials, idx-as-float
__global__ __launch_bounds__(256) void k_gather(const float* __restrict__ x,
                                                const float* __restrict__ emb,
                                                const int* __restrict__ idx,
                                                float* __restrict__ out,
                                                float* __restrict__ lossp) {
    int t = blockIdx.x * 256 + threadIdx.x;
    float ls = 0.f;
    #pragma unroll
    for (int s = 0; s < 4; ++s) {
        int i4 = t + s * 524288;
        int n = i4 >> 6, c4 = i4 & 63;
        int id = idx[n];
        float4 f = ((const float4*)x)[i4];
        float4 q = ((const float4*)emb)[id * 64 + c4];
        float dx = q.x - f.x, dy = q.y - f.y, dz = q.z - f.z, dw = q.w - f.w;
        float4 o = make_float4(f.x + dx, f.y + dy, f.z + dz, f.w + dw);
        ((float4*)out)[i4] = o;
        ls += dx*dx + dy*dy + dz*dz + dw*dw;
        if (c4 == 0) out[NQ + 1 + n] = (float)id;
    }
    #pragma unroll
    for (int o = 32; o; o >>= 1) ls += __shfl_xor(ls, o);
    __shared__ float wsum[4];
    int wid = threadIdx.x >> 6, lane = threadIdx.x & 63;
    if (lane == 0) wsum[wid] = ls;
    __syncthreads();
    if (threadIdx.x == 0) lossp[blockIdx.x] = wsum[0] + wsum[1] + wsum[2] + wsum[3];
}

__global__ __launch_bounds__(256) void k_finalize(const float* __restrict__ lossp,
                                                  float* __restrict__ out) {
    double s = 0;
    for (int i = threadIdx.x; i < 2048; i += 256) s += (double)lossp[i];
    #pragma unroll
    for (int o = 32; o; o >>= 1) s += __shfl_xor(s, o);
    __shared__ double wd[4];
    int wid = threadIdx.x >> 6, lane = threadIdx.x & 63;
    if (lane == 0) wd[wid] = s;
    __syncthreads();
    if (threadIdx.x == 0)
        out[NQ] = (float)(0.25 * ((wd[0] + wd[1] + wd[2] + wd[3]) / (double)NQ));
}

extern "C" void kernel_launch(void* const* d_in, const int* in_sizes, int n_in,
                              void* d_out, int out_size, void* d_ws, size_t ws_size,
                              hipStream_t stream) {
    const float* x   = (const float*)d_in[0];
    const float* emb = (const float*)d_in[1];
    char* ws = (char*)d_ws;
    _Float16* eh0 = (_Float16*)(ws + WS_EH0);
    float* embT  = (float*)(ws + WS_EMBT);
    float* sume  = (float*)(ws + WS_SUME);
    float* einv  = (float*)(ws + WS_EINV);
    float* xinv  = (float*)(ws + WS_XINV);
    int*   idx   = (int*)  (ws + WS_IDX);
    int*   rca   = (int*)  (ws + WS_RCA);
    int2*  rla   = (int2*) (ws + WS_RLA);
    int*   rcb   = (int*)  (ws + WS_RCB);
    int*   rlb   = (int*)  (ws + WS_RLB);
    uint64_t* bestu = (uint64_t*)(ws + WS_BEST);
    float* lossp = (float*)(ws + WS_LOSSP);
    float* out = (float*)d_out;

    hipLaunchKernelGGL(k_init,     dim3(1),        dim3(64),  0, stream, rca, rcb);
    hipLaunchKernelGGL(k_norm_x,   dim3(NPTS/4),   dim3(256), 0, stream, x, xinv);
    hipLaunchKernelGGL(k_norm_e,   dim3(KCB/4),    dim3(256), 0, stream, emb, eh0, sume, einv);
    hipLaunchKernelGGL(k_phase1,   dim3(NPTS/64),  dim3(256), 0, stream,
                       x, xinv, eh0, sume, idx, rca, rla, rcb, rlb);
    hipLaunchKernelGGL(k_transpose,dim3(256),      dim3(256), 0, stream, emb, einv, embT);
    hipLaunchKernelGGL(k_binit,    dim3(CAPB/256), dim3(256), 0, stream, bestu);
    hipLaunchKernelGGL(k_cand,     dim3(1024),     dim3(256), 0, stream,
                       x, emb, xinv, einv, sume, rca, rla, idx);
    hipLaunchKernelGGL(k_full,     dim3(2048),     dim3(256), 0, stream,
                       x, embT, xinv, sume, rcb, rlb, bestu);
    hipLaunchKernelGGL(k_ffin,     dim3(16),       dim3(256), 0, stream, rcb, rlb, bestu, idx);
    hipLaunchKernelGGL(k_gather,   dim3(2048),     dim3(256), 0, stream,
                       x, emb, idx, out, lossp);
    hipLaunchKernelGGL(k_finalize, dim3(1),        dim3(256), 0, stream, lossp, out);
}

// Round 11
// 251.581 us; speedup vs baseline: 3.0722x; 1.1069x over previous
//
#include <hip/hip_runtime.h>
#include <math.h>
#include <stdint.h>
#include <limits.h>

#define NPTS 32768
#define DIM  256
#define KCB  4096
#define NQ   (NPTS*DIM)

#define EPSN    1e-12f
#define MARGIN1 6.0e-4f
#define F16MIN  6.103515625e-05f
#define CAPB    4096
#define KINIT   0x7F800000FFFFFFFFull   /* packed (+INF, k=~0) */

typedef __attribute__((ext_vector_type(8))) _Float16 f16x8;
typedef __attribute__((ext_vector_type(4))) _Float16 f16x4;
typedef __attribute__((ext_vector_type(4))) float    f32x4;

// ws layout (byte offsets).
// [0,2MB): EH0 f16 codebook (phase1) -> later overwritten by embT lower half
// [2MB,4MB): TRI (phase1 out, merge in) -> later overwritten by embT upper half
// embT [0,4MB) built by k_transpose AFTER k_merge.
#define WS_EH0   0u
#define WS_TRI   2097152u
#define WS_EMBT  0u
#define WS_SUME  4194304u
#define WS_EINV  4210688u
#define WS_XINV  4227072u
#define WS_IDX   4358144u
#define WS_RCA   4489216u
#define WS_RLA   4489232u
#define WS_RCB   4751376u
#define WS_RLB   4751392u
#define WS_BEST  4882464u
#define WS_LOSSP 4915232u

__device__ inline unsigned fbits(float f){ union{float f;unsigned u;}v; v.f=f; return v.u; }
__device__ inline float bitsf(unsigned u){ union{float f;unsigned u;}v; v.u=u; return v.f; }
__device__ inline uint64_t dbits(double d){ union{double d;uint64_t u;}v; v.d=d; return v.u; }
__device__ inline _Float16 g16(float v){
    return (fabsf(v) < F16MIN) ? (_Float16)0.0f : (_Float16)v;
}
__device__ inline void gload16(const void* src, void* lds){
    __builtin_amdgcn_global_load_lds((const __attribute__((address_space(1))) void*)src,
                                     (__attribute__((address_space(3))) void*)lds, 16, 0, 0);
}

__global__ void k_init(int* rca, int* rcb) {
    if (threadIdx.x == 0) { *rca = 0; *rcb = 0; }
}

__global__ __launch_bounds__(256) void k_norm_x(const float* __restrict__ x,
                                                float* __restrict__ xinv) {
    int w = threadIdx.x >> 6, l = threadIdx.x & 63;
    int row = blockIdx.x * 4 + w;
    float4 v = ((const float4*)x)[row * 64 + l];
    float s = v.x*v.x + v.y*v.y + v.z*v.z + v.w*v.w;
    #pragma unroll
    for (int o = 32; o; o >>= 1) s += __shfl_xor(s, o);
    if (l == 0) xinv[row] = 1.0f / fmaxf(sqrtf(s), EPSN);
}

__global__ __launch_bounds__(256) void k_norm_e(const float* __restrict__ e,
                                                _Float16* __restrict__ eh0,
                                                float* __restrict__ sume,
                                                float* __restrict__ einv) {
    int w = threadIdx.x >> 6, l = threadIdx.x & 63;
    int row = blockIdx.x * 4 + w;
    float4 v = ((const float4*)e)[row * 64 + l];
    float s = v.x*v.x + v.y*v.y + v.z*v.z + v.w*v.w;
    #pragma unroll
    for (int o = 32; o; o >>= 1) s += __shfl_xor(s, o);
    float inv = 1.0f / fmaxf(sqrtf(s), EPSN);
    float4 n = make_float4(v.x*inv, v.y*inv, v.z*inv, v.w*inv);
    f16x4 h0; h0[0]=g16(n.x); h0[1]=g16(n.y); h0[2]=g16(n.z); h0[3]=g16(n.w);
    ((f16x4*)eh0)[row * 64 + l] = h0;
    float s2 = n.x*n.x + n.y*n.y + n.z*n.z + n.w*n.w;
    #pragma unroll
    for (int o = 32; o; o >>= 1) s2 += __shfl_xor(s2, o);
    if (l == 0) { sume[row] = s2; einv[row] = inv; }
}

// tier 1: f16 MFMA, K-split-4. Block = 128 rows x 1024 codes; 4 waves x 32 rows.
// B tile 32 codes (16KB), dbuf via literal +16384. Per row-slot tracks
// (t0,t1) u64 keys + d2 f32. Writes tri[row*4+split] = {t0, t1|flag<<12}.
__global__ __launch_bounds__(256,3) void k_phase1(
    const float* __restrict__ x, const float* __restrict__ xinv,
    const _Float16* __restrict__ eh0, const float* __restrict__ sume,
    ulonglong2* __restrict__ tri)
{
    __shared__ __align__(16) _Float16 Bs[2][32 * DIM];  // 2 x 16 KB
    const int tid = threadIdx.x;
    const int w = tid >> 6, l = tid & 63;
    const int l15 = l & 15, lhi = l >> 4;
    const int rowbase = (blockIdx.x >> 2) * 128 + w * 32;
    const int kbase   = (blockIdx.x & 3) * 1024;
    char* BsC = (char*)&Bs[0][0];

    // A fragments: 2 row-tiles resident (rows rowbase+l15, rowbase+16+l15)
    f16x8 a[2][8];
    #pragma unroll
    for (int mi = 0; mi < 2; mi++) {
        int row = rowbase + mi*16 + l15;
        float xv = xinv[row];
        const float4* xr = (const float4*)(x + row * DIM);
        #pragma unroll
        for (int dc = 0; dc < 8; dc++) {
            float4 f0 = xr[dc*8 + lhi*2];
            float4 f1 = xr[dc*8 + lhi*2 + 1];
            f16x8 av;
            av[0]=g16(f0.x*xv); av[1]=g16(f0.y*xv);
            av[2]=g16(f0.z*xv); av[3]=g16(f0.w*xv);
            av[4]=g16(f1.x*xv); av[5]=g16(f1.y*xv);
            av[6]=g16(f1.z*xv); av[7]=g16(f1.w*xv);
            a[mi][dc] = av;
        }
    }

    // hoisted per-lane LDS read offsets (compile-time indexed -> registers)
    int offs[2][8];
    #pragma unroll
    for (int ni = 0; ni < 2; ni++) {
        int col = ni*16 + l15;
        int swz = (col & 7) << 4;
        #pragma unroll
        for (int dc = 0; dc < 8; dc++)
            offs[ni][dc] = (col*512 + dc*64 + lhi*16) ^ swz;
    }

    uint64_t t0[8], t1[8];
    float d2[8];
    #pragma unroll
    for (int s = 0; s < 8; s++) { t0[s]=KINIT; t1[s]=KINIT; d2[s]=INFINITY; }

    auto stage = [&](int kt, int bufbyte) {
        #pragma unroll
        for (int r = 0; r < 4; r++) {
            int dstbyte = (r*256 + w*64 + l) << 4;
            int col = dstbyte >> 9;
            int off = dstbyte & 511;
            int srcoff = off ^ ((col & 7) << 4);
            const void* src = (const void*)((const char*)eh0
                              + (size_t)(kbase + kt*32 + col) * 512 + srcoff);
            void* dst = (void*)(BsC + bufbyte + ((r*256 + w*64) << 4));
            gload16(src, dst);
        }
    };

    auto compute = [&](int kt, int bufbyte) {
        float ses[2];
        #pragma unroll
        for (int ni = 0; ni < 2; ni++)
            ses[ni] = 4.0f + sume[kbase + kt*32 + ni*16 + l15];

        f32x4 acc[2][2];
        #pragma unroll
        for (int mi = 0; mi < 2; mi++)
            #pragma unroll
            for (int ni = 0; ni < 2; ni++)
                acc[mi][ni] = (f32x4){0.f,0.f,0.f,0.f};

        #pragma unroll
        for (int dc = 0; dc < 8; dc++) {
            #pragma unroll
            for (int ni = 0; ni < 2; ni++) {
                f16x8 b = *(const f16x8*)(BsC + bufbyte + offs[ni][dc]);
                acc[0][ni] = __builtin_amdgcn_mfma_f32_16x16x32_f16(a[0][dc], b, acc[0][ni], 0, 0, 0);
                acc[1][ni] = __builtin_amdgcn_mfma_f32_16x16x32_f16(a[1][dc], b, acc[1][ni], 0, 0, 0);
            }
        }

        #pragma unroll
        for (int ni = 0; ni < 2; ni++) {
            int col = kbase + kt*32 + ni*16 + l15;
            #pragma unroll
            for (int mi = 0; mi < 2; mi++) {
                #pragma unroll
                for (int r = 0; r < 4; r++) {
                    int s = mi*4 + r;
                    float db = ses[ni] - 2.0f * acc[mi][ni][r];   // positive
                    if (db < d2[s]) {                              // rare after warmup
                        uint64_t key = ((uint64_t)fbits(db) << 32) | (unsigned)col;
                        if (key < t1[s]) {
                            d2[s] = bitsf((unsigned)(t1[s] >> 32));
                            if (key < t0[s]) { t1[s] = t0[s]; t0[s] = key; }
                            else t1[s] = key;
                        } else {
                            d2[s] = db;
                        }
                    }
                }
            }
        }
    };

    stage(0, 0);
    for (int kt = 0; kt < 32; kt += 2) {
        __syncthreads();                    // tile kt staged; prev reads done
        stage(kt + 1, 16384);
        compute(kt, 0);
        __syncthreads();                    // tile kt+1 staged
        if (kt + 2 < 32) stage(kt + 2, 0);
        compute(kt + 1, 16384);
    }

    // merge (t0,t1,d2) across the 16 col-lanes (exact top-3 network)
    #pragma unroll
    for (int s = 0; s < 8; s++) {
        uint64_t a0 = t0[s], a1 = t1[s];
        float a2 = d2[s];
        #pragma unroll
        for (int m = 1; m < 16; m <<= 1) {
            uint64_t b0 = __shfl_xor(a0, m), b1 = __shfl_xor(a1, m);
            float    b2 = __shfl_xor(a2, m);
            uint64_t lo  = a0 < b0 ? a0 : b0;
            uint64_t hi0 = a0 < b0 ? b0 : a0;
            uint64_t lo1 = a1 < b1 ? a1 : b1;
            uint64_t mid = hi0 > lo1 ? hi0 : lo1;   // 3rd of the 4 keys
            a1 = hi0 < lo1 ? hi0 : lo1;
            a0 = lo;
            a2 = fminf(fminf(a2, b2), bitsf((unsigned)(mid >> 32)));
        }
        t0[s] = a0; t1[s] = a1; d2[s] = a2;
    }

    if (l15 == 0) {
        const int split = blockIdx.x & 3;
        #pragma unroll
        for (int s = 0; s < 8; s++) {
            int mi = s >> 2, r = s & 3;
            int row = rowbase + mi*16 + lhi*4 + r;
            float d0 = bitsf((unsigned)(t0[s] >> 32));
            uint64_t flag = (d2[s] - d0 < MARGIN1) ? (1ull << 12) : 0ull;
            ulonglong2 ent;
            ent.x = t0[s];
            ent.y = t1[s] | flag;
            tri[(row << 2) | split] = ent;
        }
    }
}

// merge 4 K-splits per row: exact global top-2 + 3rd-of-8 estimate + flags.
__global__ __launch_bounds__(256) void k_merge(
    const ulonglong2* __restrict__ tri,
    int* __restrict__ idx,
    int* __restrict__ rca, int2* __restrict__ rla,
    int* __restrict__ rcb, int* __restrict__ rlb)
{
    int row = blockIdx.x * 256 + threadIdx.x;
    ulonglong2 e0 = tri[row*4 + 0];
    ulonglong2 e1 = tri[row*4 + 1];
    ulonglong2 e2 = tri[row*4 + 2];
    ulonglong2 e3 = tri[row*4 + 3];

    uint64_t c0 = e0.x, c1 = e0.y & ~0x1000ull;
    float c2 = INFINITY;
    auto fold = [&](uint64_t b0, uint64_t b1) {
        b1 &= ~0x1000ull;                         // strip flag bit for ordering
        uint64_t lo  = c0 < b0 ? c0 : b0;
        uint64_t hi0 = c0 < b0 ? b0 : c0;
        uint64_t lo1 = c1 < b1 ? c1 : b1;
        uint64_t mid = hi0 > lo1 ? hi0 : lo1;
        c1 = hi0 < lo1 ? hi0 : lo1;
        c0 = lo;
        c2 = fminf(c2, bitsf((unsigned)(mid >> 32)));
    };
    fold(e1.x, e1.y);
    fold(e2.x, e2.y);
    fold(e3.x, e3.y);

    int k0 = (int)((unsigned)c0 & 0xFFFu);
    idx[row] = k0;
    float d0 = bitsf((unsigned)(c0 >> 32));
    float d1 = bitsf((unsigned)(c1 >> 32));
    bool lA = (d1 - d0 < MARGIN1);
    bool lB = (c2 - d0 < MARGIN1);
    // conservative: any split whose own top-3 were within margin of ITS best,
    // and whose best is within margin of the global best
    if ((e0.y >> 12) & 1) lB |= (bitsf((unsigned)(e0.x >> 32)) - d0 < MARGIN1);
    if ((e1.y >> 12) & 1) lB |= (bitsf((unsigned)(e1.x >> 32)) - d0 < MARGIN1);
    if ((e2.y >> 12) & 1) lB |= (bitsf((unsigned)(e2.x >> 32)) - d0 < MARGIN1);
    if ((e3.y >> 12) & 1) lB |= (bitsf((unsigned)(e3.x >> 32)) - d0 < MARGIN1);

    if (lA) {
        int k1 = (int)((unsigned)c1 & 0xFFFu);
        int p = atomicAdd(rca, 1);
        if (p < NPTS) rla[p] = make_int2(row, k0 | (k1 << 12));
    }
    if (lB) {
        int q = atomicAdd(rcb, 1);
        if (q < CAPB) rlb[q] = row;
    }
}

// transposed normalized codebook (after k_merge; overwrites EH0+TRI region)
__global__ __launch_bounds__(256) void k_transpose(const float* __restrict__ emb,
                                                   const float* __restrict__ einv,
                                                   float* __restrict__ embT) {
    __shared__ float tile[64][65];
    const int tid = threadIdx.x;
    const int kb = (blockIdx.x & 63) * 64;
    const int db = (blockIdx.x >> 6) * 64;
    #pragma unroll
    for (int s = 0; s < 16; s++) {
        int i = s * 256 + tid;
        int lk = i >> 6, ld = i & 63;
        tile[lk][ld] = emb[(kb + lk) * DIM + db + ld] * einv[kb + lk];
    }
    __syncthreads();
    #pragma unroll
    for (int s = 0; s < 16; s++) {
        int i = s * 256 + tid;
        int ld = i >> 6, lk = i & 63;
        embT[(db + ld) * KCB + kb + lk] = tile[lk][ld];
    }
}

// tier 2a: f64 rescore of the 2 provable candidates, one wave per flagged row
__global__ __launch_bounds__(256) void k_cand(
    const float* __restrict__ x, const float* __restrict__ emb,
    const float* __restrict__ xinv, const float* __restrict__ einv,
    const float* __restrict__ sume,
    const int* __restrict__ rca, const int2* __restrict__ rla,
    int* __restrict__ idx)
{
    int cnt = *rca; if (cnt > NPTS) cnt = NPTS;
    const int w = threadIdx.x >> 6, l = threadIdx.x & 63;
    for (int r = blockIdx.x * 4 + w; r < cnt; r += gridDim.x * 4) {
        int2 ent = rla[r];
        int row = ent.x;
        int k0 = ent.y & 0xFFF, k1 = (ent.y >> 12) & 0xFFF;
        float xv = xinv[row];
        float4 xf = ((const float4*)x)[row * 64 + l];
        double x0 = (double)xf.x * (double)xv, x1 = (double)xf.y * (double)xv;
        double x2 = (double)xf.z * (double)xv, x3 = (double)xf.w * (double)xv;
        int ks[2] = {k0, k1};
        double d[2];
        #pragma unroll
        for (int c = 0; c < 2; c++) {
            int k = ks[c];
            float ev = einv[k];
            float4 e4 = ((const float4*)emb)[k * 64 + l];
            d[c] = x0 * (double)(e4.x * ev) + x1 * (double)(e4.y * ev)
                 + x2 * (double)(e4.z * ev) + x3 * (double)(e4.w * ev);
        }
        #pragma unroll
        for (int o = 32; o; o >>= 1) {
            d[0] += __shfl_xor(d[0], o);
            d[1] += __shfl_xor(d[1], o);
        }
        if (l == 0) {
            double dist0 = 4.0 + (double)sume[k0] - 2.0 * d[0];
            double dist1 = 4.0 + (double)sume[k1] - 2.0 * d[1];
            uint64_t key0 = (dbits(dist0) & 0xFFFFFFFFFFFFF000ull) | (unsigned)k0;
            uint64_t key1 = (dbits(dist1) & 0xFFFFFFFFFFFFF000ull) | (unsigned)k1;
            idx[row] = (int)((key0 < key1 ? key0 : key1) & 0xFFFull);
        }
    }
}

__global__ __launch_bounds__(256) void k_binit(uint64_t* __restrict__ bestu) {
    bestu[blockIdx.x * 256 + threadIdx.x] = ~0ull;
}

// tier 2b: full-K f64, shuffle-free coalesced, block=(row,chunk), atomicMin
__global__ __launch_bounds__(256) void k_full(
    const float* __restrict__ x, const float* __restrict__ embT,
    const float* __restrict__ xinv, const float* __restrict__ sume,
    const int* __restrict__ rcb, const int* __restrict__ rlb,
    uint64_t* __restrict__ bestu)
{
    __shared__ float xs[DIM];
    int cnt = *rcb; if (cnt > CAPB) cnt = CAPB; if (cnt <= 0) return;
    int items = cnt * 16;
    const int tid = threadIdx.x;
    for (int item = blockIdx.x; item < items; item += gridDim.x) {
        int r = item >> 4, chunk = item & 15;
        int row = rlb[r];
        __syncthreads();
        xs[tid] = x[row * DIM + tid] * xinv[row];
        __syncthreads();
        int k = chunk * 256 + tid;
        const float* et = embT + k;
        double dp0 = 0, dp1 = 0, dp2 = 0, dp3 = 0;
        #pragma unroll 8
        for (int d = 0; d < DIM; d += 4) {
            dp0 += (double)xs[d+0] * (double)et[(d+0) * KCB];
            dp1 += (double)xs[d+1] * (double)et[(d+1) * KCB];
            dp2 += (double)xs[d+2] * (double)et[(d+2) * KCB];
            dp3 += (double)xs[d+3] * (double)et[(d+3) * KCB];
        }
        double dist = 4.0 + (double)sume[k] - 2.0 * ((dp0 + dp1) + (dp2 + dp3));
        uint64_t key = (dbits(dist) & 0xFFFFFFFFFFFFF000ull) | (unsigned)k;
        atomicMin((unsigned long long*)&bestu[r], (unsigned long long)key);
    }
}

__global__ __launch_bounds__(256) void k_ffin(const int* __restrict__ rcb,
                                              const int* __restrict__ rlb,
                                              const uint64_t* __restrict__ bestu,
                                              int* __restrict__ idx) {
    int cnt = *rcb; if (cnt > CAPB) cnt = CAPB;
    int i = blockIdx.x * 256 + threadIdx.x;
    if (i < cnt) idx[rlb[i]] = (int)(bestu[i] & 0xFFFull);
}

// gather raw embeddings, straight-through output, loss partials, idx-as-float
__global__ __launch_bounds__(256) void k_gather(const float* __restrict__ x,
                                                const float* __restrict__ emb,
                                                const int* __restrict__ idx,
                                                float* __restrict__ out,
                                                float* __restrict__ lossp) {
    int t = blockIdx.x * 256 + threadIdx.x;
    float ls = 0.f;
    #pragma unroll
    for (int s = 0; s < 4; ++s) {
        int i4 = t + s * 524288;
        int n = i4 >> 6, c4 = i4 & 63;
        int id = idx[n];
        float4 f = ((const float4*)x)[i4];
        float4 q = ((const float4*)emb)[id * 64 + c4];
        float dx = q.x - f.x, dy = q.y - f.y, dz = q.z - f.z, dw = q.w - f.w;
        float4 o = make_float4(f.x + dx, f.y + dy, f.z + dz, f.w + dw);
        ((float4*)out)[i4] = o;
        ls += dx*dx + dy*dy + dz*dz + dw*dw;
        if (c4 == 0) out[NQ + 1 + n] = (float)id;
    }
    #pragma unroll
    for (int o = 32; o; o >>= 1) ls += __shfl_xor(ls, o);
    __shared__ float wsum[4];
    int wid = threadIdx.x >> 6, lane = threadIdx.x & 63;
    if (lane == 0) wsum[wid] = ls;
    __syncthreads();
    if (threadIdx.x == 0) lossp[blockIdx.x] = wsum[0] + wsum[1] + wsum[2] + wsum[3];
}

__global__ __launch_bounds__(256) void k_finalize(const float* __restrict__ lossp,
                                                  float* __restrict__ out) {
    double s = 0;
    for (int i = threadIdx.x; i < 2048; i += 256) s += (double)lossp[i];
    #pragma unroll
    for (int o = 32; o; o >>= 1) s += __shfl_xor(s, o);
    __shared__ double wd[4];
    int wid = threadIdx.x >> 6, lane = threadIdx.x & 63;
    if (lane == 0) wd[wid] = s;
    __syncthreads();
    if (threadIdx.x == 0)
        out[NQ] = (float)(0.25 * ((wd[0] + wd[1] + wd[2] + wd[3]) / (double)NQ));
}

extern "C" void kernel_launch(void* const* d_in, const int* in_sizes, int n_in,
                              void* d_out, int out_size, void* d_ws, size_t ws_size,
                              hipStream_t stream) {
    const float* x   = (const float*)d_in[0];
    const float* emb = (const float*)d_in[1];
    char* ws = (char*)d_ws;
    _Float16* eh0 = (_Float16*)(ws + WS_EH0);
    ulonglong2* tri = (ulonglong2*)(ws + WS_TRI);
    float* embT  = (float*)(ws + WS_EMBT);
    float* sume  = (float*)(ws + WS_SUME);
    float* einv  = (float*)(ws + WS_EINV);
    float* xinv  = (float*)(ws + WS_XINV);
    int*   idx   = (int*)  (ws + WS_IDX);
    int*   rca   = (int*)  (ws + WS_RCA);
    int2*  rla   = (int2*) (ws + WS_RLA);
    int*   rcb   = (int*)  (ws + WS_RCB);
    int*   rlb   = (int*)  (ws + WS_RLB);
    uint64_t* bestu = (uint64_t*)(ws + WS_BEST);
    float* lossp = (float*)(ws + WS_LOSSP);
    float* out = (float*)d_out;

    hipLaunchKernelGGL(k_init,     dim3(1),          dim3(64),  0, stream, rca, rcb);
    hipLaunchKernelGGL(k_norm_x,   dim3(NPTS/4),     dim3(256), 0, stream, x, xinv);
    hipLaunchKernelGGL(k_norm_e,   dim3(KCB/4),      dim3(256), 0, stream, emb, eh0, sume, einv);
    hipLaunchKernelGGL(k_phase1,   dim3(NPTS/128*4), dim3(256), 0, stream,
                       x, xinv, eh0, sume, tri);
    hipLaunchKernelGGL(k_merge,    dim3(NPTS/256),   dim3(256), 0, stream,
                       tri, idx, rca, rla, rcb, rlb);
    hipLaunchKernelGGL(k_transpose,dim3(256),        dim3(256), 0, stream, emb, einv, embT);
    hipLaunchKernelGGL(k_binit,    dim3(CAPB/256),   dim3(256), 0, stream, bestu);
    hipLaunchKernelGGL(k_cand,     dim3(1024),       dim3(256), 0, stream,
                       x, emb, xinv, einv, sume, rca, rla, idx);
    hipLaunchKernelGGL(k_full,     dim3(2048),       dim3(256), 0, stream,
                       x, embT, xinv, sume, rcb, rlb, bestu);
    hipLaunchKernelGGL(k_ffin,     dim3(16),         dim3(256), 0, stream, rcb, rlb, bestu, idx);
    hipLaunchKernelGGL(k_gather,   dim3(2048),       dim3(256), 0, stream,
                       x, emb, idx, out, lossp);
    hipLaunchKernelGGL(k_finalize, dim3(1),          dim3(256), 0, stream, lossp, out);
}

// Round 12
// 183.288 us; speedup vs baseline: 4.2169x; 1.3726x over previous
//
#include <hip/hip_runtime.h>
#include <math.h>
#include <stdint.h>
#include <limits.h>

#define NPTS 32768
#define DIM  256
#define KCB  4096
#define NQ   (NPTS*DIM)

#define EPSN    1e-12f
#define MARGIN1 6.0e-4f
#define F16MIN  6.103515625e-05f
#define CAPB    4096
#define KINIT   0x7F800000FFFFFFFFull   /* packed (+INF, k=~0) */

typedef __attribute__((ext_vector_type(8))) _Float16 f16x8;
typedef __attribute__((ext_vector_type(4))) _Float16 f16x4;
typedef __attribute__((ext_vector_type(4))) float    f32x4;

// ws layout (byte offsets).
// [0,2MB): EH0 f16 codebook (phase1) -> later overwritten by embT lower half
// [2MB,4MB): TRI (phase1 out, merge in) -> later overwritten by embT upper half
#define WS_EH0   0u
#define WS_TRI   2097152u
#define WS_EMBT  0u
#define WS_SUME  4194304u
#define WS_EINV  4210688u
#define WS_XINV  4227072u
#define WS_IDX   4358144u
#define WS_RCA   4489216u
#define WS_RLA   4489232u
#define WS_RCB   4751376u
#define WS_RLB   4751392u
#define WS_BEST  4882464u
#define WS_LOSSP 4915232u

__device__ inline unsigned fbits(float f){ union{float f;unsigned u;}v; v.f=f; return v.u; }
__device__ inline float bitsf(unsigned u){ union{float f;unsigned u;}v; v.u=u; return v.f; }
__device__ inline uint64_t dbits(double d){ union{double d;uint64_t u;}v; v.d=d; return v.u; }
__device__ inline _Float16 g16(float v){
    return (fabsf(v) < F16MIN) ? (_Float16)0.0f : (_Float16)v;
}
__device__ inline void gload16(const void* src, void* lds){
    __builtin_amdgcn_global_load_lds((const __attribute__((address_space(1))) void*)src,
                                     (__attribute__((address_space(3))) void*)lds, 16, 0, 0);
}

__global__ void k_init(int* rca, int* rcb) {
    if (threadIdx.x == 0) { *rca = 0; *rcb = 0; }
}

__global__ __launch_bounds__(256) void k_norm_x(const float* __restrict__ x,
                                                float* __restrict__ xinv) {
    int w = threadIdx.x >> 6, l = threadIdx.x & 63;
    int row = blockIdx.x * 4 + w;
    float4 v = ((const float4*)x)[row * 64 + l];
    float s = v.x*v.x + v.y*v.y + v.z*v.z + v.w*v.w;
    #pragma unroll
    for (int o = 32; o; o >>= 1) s += __shfl_xor(s, o);
    if (l == 0) xinv[row] = 1.0f / fmaxf(sqrtf(s), EPSN);
}

__global__ __launch_bounds__(256) void k_norm_e(const float* __restrict__ e,
                                                _Float16* __restrict__ eh0,
                                                float* __restrict__ sume,
                                                float* __restrict__ einv) {
    int w = threadIdx.x >> 6, l = threadIdx.x & 63;
    int row = blockIdx.x * 4 + w;
    float4 v = ((const float4*)e)[row * 64 + l];
    float s = v.x*v.x + v.y*v.y + v.z*v.z + v.w*v.w;
    #pragma unroll
    for (int o = 32; o; o >>= 1) s += __shfl_xor(s, o);
    float inv = 1.0f / fmaxf(sqrtf(s), EPSN);
    float4 n = make_float4(v.x*inv, v.y*inv, v.z*inv, v.w*inv);
    f16x4 h0; h0[0]=g16(n.x); h0[1]=g16(n.y); h0[2]=g16(n.z); h0[3]=g16(n.w);
    ((f16x4*)eh0)[row * 64 + l] = h0;
    float s2 = n.x*n.x + n.y*n.y + n.z*n.z + n.w*n.w;
    #pragma unroll
    for (int o = 32; o; o >>= 1) s2 += __shfl_xor(s2, o);
    if (l == 0) { sume[row] = s2; einv[row] = inv; }
}

// tier 1: f16 MFMA with SWAPPED operands: D[code][xrow] = mfma(B_codes, A_rows).
// Wave owns 64 rows (4 groups x 16); lane's C-col = fixed row l15 => only 4
// tracking slots/lane with exact per-row top-2 + d2. K-split 4, 32-code dbuf
// tiles, 16 ds_read -> 64 MFMA per ktile.
__global__ __launch_bounds__(256,2) void k_phase1(
    const float* __restrict__ x, const float* __restrict__ xinv,
    const _Float16* __restrict__ eh0, const float* __restrict__ sume,
    ulonglong2* __restrict__ tri)
{
    __shared__ __align__(16) _Float16 Bs[2][32 * DIM];  // 2 x 16 KB
    const int tid = threadIdx.x;
    const int w = tid >> 6, l = tid & 63;
    const int l15 = l & 15, lhi = l >> 4;
    const int rowbase = (blockIdx.x >> 2) * 256 + w * 64;
    const int kbase   = (blockIdx.x & 3) * 1024;
    char* BsC = (char*)&Bs[0][0];

    // A (row) fragments: lane holds x_norm[row=rowbase+g*16+l15][d=dc*32+lhi*8+j]
    f16x8 a[4][8];
    #pragma unroll
    for (int g = 0; g < 4; g++) {
        int row = rowbase + g*16 + l15;
        float xv = xinv[row];
        const float4* xr = (const float4*)(x + row * DIM);
        #pragma unroll
        for (int dc = 0; dc < 8; dc++) {
            float4 f0 = xr[dc*8 + lhi*2];
            float4 f1 = xr[dc*8 + lhi*2 + 1];
            f16x8 av;
            av[0]=g16(f0.x*xv); av[1]=g16(f0.y*xv);
            av[2]=g16(f0.z*xv); av[3]=g16(f0.w*xv);
            av[4]=g16(f1.x*xv); av[5]=g16(f1.y*xv);
            av[6]=g16(f1.z*xv); av[7]=g16(f1.w*xv);
            a[g][dc] = av;
        }
    }

    // hoisted LDS read offsets for the code (B) fragments
    int offs[2][8];
    #pragma unroll
    for (int ni = 0; ni < 2; ni++) {
        int col = ni*16 + l15;
        int swz = (col & 7) << 4;
        #pragma unroll
        for (int dc = 0; dc < 8; dc++)
            offs[ni][dc] = (col*512 + dc*64 + lhi*16) ^ swz;
    }

    // per-lane tracking: slot g <-> row rowbase + g*16 + l15
    uint64_t t0[4], t1[4];
    float d2[4];
    #pragma unroll
    for (int g = 0; g < 4; g++) { t0[g]=KINIT; t1[g]=KINIT; d2[g]=INFINITY; }

    auto stage = [&](int kt, int bufbyte) {
        #pragma unroll
        for (int p = 0; p < 4; p++) {
            int c = p*256 + w*64 + l;                // 16B chunk in 16KB tile
            int col = c >> 5;                         // 512 B per code row
            int off = (c << 4) & 511;
            int srcoff = off ^ ((col & 7) << 4);
            const void* src = (const void*)((const char*)eh0
                              + (size_t)(kbase + kt*32 + col) * 512 + srcoff);
            void* dst = (void*)(BsC + bufbyte + ((p*256 + w*64) << 4));
            gload16(src, dst);
        }
    };

    auto compute = [&](int kt, int bufbyte) {
        f32x4 acc[4][2];
        #pragma unroll
        for (int g = 0; g < 4; g++)
            #pragma unroll
            for (int ni = 0; ni < 2; ni++)
                acc[g][ni] = (f32x4){0.f,0.f,0.f,0.f};

        #pragma unroll
        for (int dc = 0; dc < 8; dc++) {
            #pragma unroll
            for (int ni = 0; ni < 2; ni++) {
                f16x8 b = *(const f16x8*)(BsC + bufbyte + offs[ni][dc]);
                acc[0][ni] = __builtin_amdgcn_mfma_f32_16x16x32_f16(b, a[0][dc], acc[0][ni], 0, 0, 0);
                acc[1][ni] = __builtin_amdgcn_mfma_f32_16x16x32_f16(b, a[1][dc], acc[1][ni], 0, 0, 0);
                acc[2][ni] = __builtin_amdgcn_mfma_f32_16x16x32_f16(b, a[2][dc], acc[2][ni], 0, 0, 0);
                acc[3][ni] = __builtin_amdgcn_mfma_f32_16x16x32_f16(b, a[3][dc], acc[3][ni], 0, 0, 0);
            }
        }

        // epilogue: lane sees codes kbase+kt*32+ni*16+lhi*4+r for its row l15
        #pragma unroll
        for (int ni = 0; ni < 2; ni++) {
            float4 se4 = *(const float4*)(sume + kbase + kt*32 + ni*16 + lhi*4);
            float ses[4] = {4.0f+se4.x, 4.0f+se4.y, 4.0f+se4.z, 4.0f+se4.w};
            #pragma unroll
            for (int g = 0; g < 4; g++) {
                #pragma unroll
                for (int r = 0; r < 4; r++) {
                    float db = ses[r] - 2.0f * acc[g][ni][r];   // positive
                    if (db < d2[g]) {
                        int code = kbase + kt*32 + ni*16 + lhi*4 + r;
                        uint64_t key = ((uint64_t)fbits(db) << 32) | (unsigned)code;
                        if (key < t1[g]) {
                            d2[g] = bitsf((unsigned)(t1[g] >> 32));
                            if (key < t0[g]) { t1[g] = t0[g]; t0[g] = key; }
                            else t1[g] = key;
                        } else {
                            d2[g] = db;
                        }
                    }
                }
            }
        }
    };

    stage(0, 0);
    for (int kt = 0; kt < 32; kt += 2) {
        __syncthreads();                    // tile kt staged; prev reads done
        stage(kt + 1, 16384);
        compute(kt, 0);
        __syncthreads();                    // tile kt+1 staged
        if (kt + 2 < 32) stage(kt + 2, 0);
        compute(kt + 1, 16384);
    }

    // merge across the 4 lhi lane-groups only (2-step butterfly: m=16,32)
    #pragma unroll
    for (int g = 0; g < 4; g++) {
        uint64_t a0 = t0[g], a1 = t1[g];
        float a2 = d2[g];
        #pragma unroll
        for (int m = 16; m < 64; m <<= 1) {
            uint64_t b0 = __shfl_xor(a0, m), b1 = __shfl_xor(a1, m);
            float    b2 = __shfl_xor(a2, m);
            uint64_t lo  = a0 < b0 ? a0 : b0;
            uint64_t hi0 = a0 < b0 ? b0 : a0;
            uint64_t lo1 = a1 < b1 ? a1 : b1;
            uint64_t mid = hi0 > lo1 ? hi0 : lo1;   // 3rd of the 4 keys
            a1 = hi0 < lo1 ? hi0 : lo1;
            a0 = lo;
            a2 = fminf(fminf(a2, b2), bitsf((unsigned)(mid >> 32)));
        }
        t0[g] = a0; t1[g] = a1; d2[g] = a2;
    }

    if (lhi == 0) {
        const int split = blockIdx.x & 3;
        #pragma unroll
        for (int g = 0; g < 4; g++) {
            int row = rowbase + g*16 + l15;
            float d0 = bitsf((unsigned)(t0[g] >> 32));
            uint64_t flag = (d2[g] - d0 < MARGIN1) ? (1ull << 12) : 0ull;
            ulonglong2 ent;
            ent.x = t0[g];
            ent.y = t1[g] | flag;
            tri[(row << 2) | split] = ent;
        }
    }
}

// merge 4 K-splits per row: exact global top-2 + 3rd-of-8 estimate + flags.
__global__ __launch_bounds__(256) void k_merge(
    const ulonglong2* __restrict__ tri,
    int* __restrict__ idx,
    int* __restrict__ rca, int2* __restrict__ rla,
    int* __restrict__ rcb, int* __restrict__ rlb)
{
    int row = blockIdx.x * 256 + threadIdx.x;
    ulonglong2 e0 = tri[row*4 + 0];
    ulonglong2 e1 = tri[row*4 + 1];
    ulonglong2 e2 = tri[row*4 + 2];
    ulonglong2 e3 = tri[row*4 + 3];

    uint64_t c0 = e0.x, c1 = e0.y & ~0x1000ull;
    float c2 = INFINITY;
    auto fold = [&](uint64_t b0, uint64_t b1) {
        b1 &= ~0x1000ull;                         // strip flag bit for ordering
        uint64_t lo  = c0 < b0 ? c0 : b0;
        uint64_t hi0 = c0 < b0 ? b0 : c0;
        uint64_t lo1 = c1 < b1 ? c1 : b1;
        uint64_t mid = hi0 > lo1 ? hi0 : lo1;
        c1 = hi0 < lo1 ? hi0 : lo1;
        c0 = lo;
        c2 = fminf(c2, bitsf((unsigned)(mid >> 32)));
    };
    fold(e1.x, e1.y);
    fold(e2.x, e2.y);
    fold(e3.x, e3.y);

    int k0 = (int)((unsigned)c0 & 0xFFFu);
    idx[row] = k0;
    float d0 = bitsf((unsigned)(c0 >> 32));
    float d1 = bitsf((unsigned)(c1 >> 32));
    bool lA = (d1 - d0 < MARGIN1);
    bool lB = (c2 - d0 < MARGIN1);
    if ((e0.y >> 12) & 1) lB |= (bitsf((unsigned)(e0.x >> 32)) - d0 < MARGIN1);
    if ((e1.y >> 12) & 1) lB |= (bitsf((unsigned)(e1.x >> 32)) - d0 < MARGIN1);
    if ((e2.y >> 12) & 1) lB |= (bitsf((unsigned)(e2.x >> 32)) - d0 < MARGIN1);
    if ((e3.y >> 12) & 1) lB |= (bitsf((unsigned)(e3.x >> 32)) - d0 < MARGIN1);

    if (lA) {
        int k1 = (int)((unsigned)c1 & 0xFFFu);
        int p = atomicAdd(rca, 1);
        if (p < NPTS) rla[p] = make_int2(row, k0 | (k1 << 12));
    }
    if (lB) {
        int q = atomicAdd(rcb, 1);
        if (q < CAPB) rlb[q] = row;
    }
}

// transposed normalized codebook (after k_merge; overwrites EH0+TRI region)
__global__ __launch_bounds__(256) void k_transpose(const float* __restrict__ emb,
                                                   const float* __restrict__ einv,
                                                   float* __restrict__ embT) {
    __shared__ float tile[64][65];
    const int tid = threadIdx.x;
    const int kb = (blockIdx.x & 63) * 64;
    const int db = (blockIdx.x >> 6) * 64;
    #pragma unroll
    for (int s = 0; s < 16; s++) {
        int i = s * 256 + tid;
        int lk = i >> 6, ld = i & 63;
        tile[lk][ld] = emb[(kb + lk) * DIM + db + ld] * einv[kb + lk];
    }
    __syncthreads();
    #pragma unroll
    for (int s = 0; s < 16; s++) {
        int i = s * 256 + tid;
        int ld = i >> 6, lk = i & 63;
        embT[(db + ld) * KCB + kb + lk] = tile[lk][ld];
    }
}

// tier 2a: f64 rescore of the 2 provable candidates, one wave per flagged row
__global__ __launch_bounds__(256) void k_cand(
    const float* __restrict__ x, const float* __restrict__ emb,
    const float* __restrict__ xinv, const float* __restrict__ einv,
    const float* __restrict__ sume,
    const int* __restrict__ rca, const int2* __restrict__ rla,
    int* __restrict__ idx)
{
    int cnt = *rca; if (cnt > NPTS) cnt = NPTS;
    const int w = threadIdx.x >> 6, l = threadIdx.x & 63;
    for (int r = blockIdx.x * 4 + w; r < cnt; r += gridDim.x * 4) {
        int2 ent = rla[r];
        int row = ent.x;
        int k0 = ent.y & 0xFFF, k1 = (ent.y >> 12) & 0xFFF;
        float xv = xinv[row];
        float4 xf = ((const float4*)x)[row * 64 + l];
        double x0 = (double)xf.x * (double)xv, x1 = (double)xf.y * (double)xv;
        double x2 = (double)xf.z * (double)xv, x3 = (double)xf.w * (double)xv;
        int ks[2] = {k0, k1};
        double d[2];
        #pragma unroll
        for (int c = 0; c < 2; c++) {
            int k = ks[c];
            float ev = einv[k];
            float4 e4 = ((const float4*)emb)[k * 64 + l];
            d[c] = x0 * (double)(e4.x * ev) + x1 * (double)(e4.y * ev)
                 + x2 * (double)(e4.z * ev) + x3 * (double)(e4.w * ev);
        }
        #pragma unroll
        for (int o = 32; o; o >>= 1) {
            d[0] += __shfl_xor(d[0], o);
            d[1] += __shfl_xor(d[1], o);
        }
        if (l == 0) {
            double dist0 = 4.0 + (double)sume[k0] - 2.0 * d[0];
            double dist1 = 4.0 + (double)sume[k1] - 2.0 * d[1];
            uint64_t key0 = (dbits(dist0) & 0xFFFFFFFFFFFFF000ull) | (unsigned)k0;
            uint64_t key1 = (dbits(dist1) & 0xFFFFFFFFFFFFF000ull) | (unsigned)k1;
            idx[row] = (int)((key0 < key1 ? key0 : key1) & 0xFFFull);
        }
    }
}

__global__ __launch_bounds__(256) void k_binit(uint64_t* __restrict__ bestu) {
    bestu[blockIdx.x * 256 + threadIdx.x] = ~0ull;
}

// tier 2b: full-K f64, shuffle-free coalesced, block=(row,chunk), atomicMin
__global__ __launch_bounds__(256) void k_full(
    const float* __restrict__ x, const float* __restrict__ embT,
    const float* __restrict__ xinv, const float* __restrict__ sume,
    const int* __restrict__ rcb, const int* __restrict__ rlb,
    uint64_t* __restrict__ bestu)
{
    __shared__ float xs[DIM];
    int cnt = *rcb; if (cnt > CAPB) cnt = CAPB; if (cnt <= 0) return;
    int items = cnt * 16;
    const int tid = threadIdx.x;
    for (int item = blockIdx.x; item < items; item += gridDim.x) {
        int r = item >> 4, chunk = item & 15;
        int row = rlb[r];
        __syncthreads();
        xs[tid] = x[row * DIM + tid] * xinv[row];
        __syncthreads();
        int k = chunk * 256 + tid;
        const float* et = embT + k;
        double dp0 = 0, dp1 = 0, dp2 = 0, dp3 = 0;
        #pragma unroll 8
        for (int d = 0; d < DIM; d += 4) {
            dp0 += (double)xs[d+0] * (double)et[(d+0) * KCB];
            dp1 += (double)xs[d+1] * (double)et[(d+1) * KCB];
            dp2 += (double)xs[d+2] * (double)et[(d+2) * KCB];
            dp3 += (double)xs[d+3] * (double)et[(d+3) * KCB];
        }
        double dist = 4.0 + (double)sume[k] - 2.0 * ((dp0 + dp1) + (dp2 + dp3));
        uint64_t key = (dbits(dist) & 0xFFFFFFFFFFFFF000ull) | (unsigned)k;
        atomicMin((unsigned long long*)&bestu[r], (unsigned long long)key);
    }
}

__global__ __launch_bounds__(256) void k_ffin(const int* __restrict__ rcb,
                                              const int* __restrict__ rlb,
                                              const uint64_t* __restrict__ bestu,
                                              int* __restrict__ idx) {
    int cnt = *rcb; if (cnt > CAPB) cnt = CAPB;
    int i = blockIdx.x * 256 + threadIdx.x;
    if (i < cnt) idx[rlb[i]] = (int)(bestu[i] & 0xFFFull);
}

// gather raw embeddings, straight-through output, loss partials, idx-as-float
__global__ __launch_bounds__(256) void k_gather(const float* __restrict__ x,
                                                const float* __restrict__ emb,
                                                const int* __restrict__ idx,
                                                float* __restrict__ out,
                                                float* __restrict__ lossp) {
    int t = blockIdx.x * 256 + threadIdx.x;
    float ls = 0.f;
    #pragma unroll
    for (int s = 0; s < 4; ++s) {
        int i4 = t + s * 524288;
        int n = i4 >> 6, c4 = i4 & 63;
        int id = idx[n];
        float4 f = ((const float4*)x)[i4];
        float4 q = ((const float4*)emb)[id * 64 + c4];
        float dx = q.x - f.x, dy = q.y - f.y, dz = q.z - f.z, dw = q.w - f.w;
        float4 o = make_float4(f.x + dx, f.y + dy, f.z + dz, f.w + dw);
        ((float4*)out)[i4] = o;
        ls += dx*dx + dy*dy + dz*dz + dw*dw;
        if (c4 == 0) out[NQ + 1 + n] = (float)id;
    }
    #pragma unroll
    for (int o = 32; o; o >>= 1) ls += __shfl_xor(ls, o);
    __shared__ float wsum[4];
    int wid = threadIdx.x >> 6, lane = threadIdx.x & 63;
    if (lane == 0) wsum[wid] = ls;
    __syncthreads();
    if (threadIdx.x == 0) lossp[blockIdx.x] = wsum[0] + wsum[1] + wsum[2] + wsum[3];
}

__global__ __launch_bounds__(256) void k_finalize(const float* __restrict__ lossp,
                                                  float* __restrict__ out) {
    double s = 0;
    for (int i = threadIdx.x; i < 2048; i += 256) s += (double)lossp[i];
    #pragma unroll
    for (int o = 32; o; o >>= 1) s += __shfl_xor(s, o);
    __shared__ double wd[4];
    int wid = threadIdx.x >> 6, lane = threadIdx.x & 63;
    if (lane == 0) wd[wid] = s;
    __syncthreads();
    if (threadIdx.x == 0)
        out[NQ] = (float)(0.25 * ((wd[0] + wd[1] + wd[2] + wd[3]) / (double)NQ));
}

extern "C" void kernel_launch(void* const* d_in, const int* in_sizes, int n_in,
                              void* d_out, int out_size, void* d_ws, size_t ws_size,
                              hipStream_t stream) {
    const float* x   = (const float*)d_in[0];
    const float* emb = (const float*)d_in[1];
    char* ws = (char*)d_ws;
    _Float16* eh0 = (_Float16*)(ws + WS_EH0);
    ulonglong2* tri = (ulonglong2*)(ws + WS_TRI);
    float* embT  = (float*)(ws + WS_EMBT);
    float* sume  = (float*)(ws + WS_SUME);
    float* einv  = (float*)(ws + WS_EINV);
    float* xinv  = (float*)(ws + WS_XINV);
    int*   idx   = (int*)  (ws + WS_IDX);
    int*   rca   = (int*)  (ws + WS_RCA);
    int2*  rla   = (int2*) (ws + WS_RLA);
    int*   rcb   = (int*)  (ws + WS_RCB);
    int*   rlb   = (int*)  (ws + WS_RLB);
    uint64_t* bestu = (uint64_t*)(ws + WS_BEST);
    float* lossp = (float*)(ws + WS_LOSSP);
    float* out = (float*)d_out;

    hipLaunchKernelGGL(k_init,     dim3(1),          dim3(64),  0, stream, rca, rcb);
    hipLaunchKernelGGL(k_norm_x,   dim3(NPTS/4),     dim3(256), 0, stream, x, xinv);
    hipLaunchKernelGGL(k_norm_e,   dim3(KCB/4),      dim3(256), 0, stream, emb, eh0, sume, einv);
    hipLaunchKernelGGL(k_phase1,   dim3(NPTS/256*4), dim3(256), 0, stream,
                       x, xinv, eh0, sume, tri);
    hipLaunchKernelGGL(k_merge,    dim3(NPTS/256),   dim3(256), 0, stream,
                       tri, idx, rca, rla, rcb, rlb);
    hipLaunchKernelGGL(k_transpose,dim3(256),        dim3(256), 0, stream, emb, einv, embT);
    hipLaunchKernelGGL(k_binit,    dim3(CAPB/256),   dim3(256), 0, stream, bestu);
    hipLaunchKernelGGL(k_cand,     dim3(1024),       dim3(256), 0, stream,
                       x, emb, xinv, einv, sume, rca, rla, idx);
    hipLaunchKernelGGL(k_full,     dim3(2048),       dim3(256), 0, stream,
                       x, embT, xinv, sume, rcb, rlb, bestu);
    hipLaunchKernelGGL(k_ffin,     dim3(16),         dim3(256), 0, stream, rcb, rlb, bestu, idx);
    hipLaunchKernelGGL(k_gather,   dim3(2048),       dim3(256), 0, stream,
                       x, emb, idx, out, lossp);
    hipLaunchKernelGGL(k_finalize, dim3(1),          dim3(256), 0, stream, lossp, out);
}